// Round 6
// baseline (314.005 us; speedup 1.0000x reference)
//
#include <hip/hip_runtime.h>
#include <hip/hip_bf16.h>
#include <math.h>

#define NP 512
#define NW 3584
#define NT 4096
#define FIN 256
#define H1 8
#define O1 32
#define H2 8
#define O2 256
#define NEG 0.2f

typedef __attribute__((ext_vector_type(8))) short bf16x8;
typedef __attribute__((ext_vector_type(4))) float f32x4;
typedef __attribute__((ext_vector_type(2))) float v2f;
typedef unsigned long long u64;

__device__ __forceinline__ unsigned short f2bf(float f) {
    unsigned u = __float_as_uint(f);
    unsigned r = (u + 0x7FFF + ((u >> 16) & 1)) >> 16;
    return (unsigned short)r;
}

__device__ __forceinline__ float fast_tanh(float x) {
    float ex = __expf(2.0f * x);
    return 1.0f - 2.0f / (ex + 1.0f);   // saturates to +-1
}

// ================= fused prep: conv_word | gat1_hp | conv_w2 | pack_adj | cvec ========
// grid = 3584 + 256 + 2048 + 896 + 1 = 6785 blocks of 256
__global__ __launch_bounds__(256) void k_prep(
    const float* __restrict__ wf, const float* __restrict__ pf,
    const float* __restrict__ w1, const float* __restrict__ a_src1,
    const float* __restrict__ a_dst1, const float* __restrict__ w2,
    const float* __restrict__ b2, const float* __restrict__ W_fc,
    const int* __restrict__ wp_adj,
    unsigned short* __restrict__ abf, unsigned short* __restrict__ btbf,
    float* __restrict__ hp1, float* __restrict__ ss1, float* __restrict__ sd1,
    u64* __restrict__ packed, float* __restrict__ cvec)
{
    __shared__ float feat[2][FIN];
    __shared__ float red[4][5];
    int blk = blockIdx.x;
    int t = threadIdx.x;
    if (blk < 3584) {
        // conv_word
        int i = blk * 256 + t;
        abf[i] = f2bf(wf[i]);
    } else if (blk < 3840) {
        // gat1_hp: 2 rows per block
        int n0 = (blk - 3584) * 2;
        feat[0][t] = pf[n0 * FIN + t];
        feat[1][t] = pf[(n0 + 1) * FIN + t];
        __syncthreads();
        int h = t >> 5, o = t & 31;
        float acc0 = 0.f, acc1 = 0.f;
        const float* wcol = w1 + h * FIN * O1 + o;
        #pragma unroll 4
        for (int f = 0; f < FIN; f++) {
            float w = wcol[f * O1];
            acc0 += feat[0][f] * w;
            acc1 += feat[1][f] * w;
        }
        hp1[n0 * 256 + t] = acc0;
        hp1[(n0 + 1) * 256 + t] = acc1;
        float as = a_src1[h * O1 + o];
        float ad = a_dst1[h * O1 + o];
        float accs[2] = {acc0, acc1};
        #pragma unroll
        for (int i = 0; i < 2; i++) {
            float th = tanhf(accs[i]);
            float vs = th * as, vd = th * ad;
            #pragma unroll
            for (int off = 1; off < 32; off <<= 1) {
                vs += __shfl_xor(vs, off);
                vd += __shfl_xor(vd, off);
            }
            if (o == 0) { ss1[h * NP + n0 + i] = vs; sd1[h * NP + n0 + i] = vd; }
        }
    } else if (blk < 5888) {
        // conv_w2: [h][f][o] -> bf16 [h][o][f]
        int idx = (blk - 3840) * 256 + t;
        int f = idx & 255, o = (idx >> 8) & 255, h = idx >> 16;
        btbf[idx] = f2bf(w2[(h * FIN + f) * O2 + o]);
    } else if (blk < 6784) {
        // pack_adj
        int w = t >> 6, l = t & 63;
        int r = (blk - 5888) * 4 + w;
        const int4* row = (const int4*)(wp_adj + (size_t)r * NT);
        for (int c4 = 0; c4 < 16; c4++) {
            int4 x = row[c4 * 64 + l];
            u64 nib = (u64)((x.x != 0 ? 1 : 0) | (x.y != 0 ? 2 : 0) |
                            (x.z != 0 ? 4 : 0) | (x.w != 0 ? 8 : 0));
            u64 v = nib << (4 * (l & 15));
            v |= __shfl_xor(v, 1);
            v |= __shfl_xor(v, 2);
            v |= __shfl_xor(v, 4);
            v |= __shfl_xor(v, 8);
            if ((l & 15) == 0) packed[(size_t)r * 64 + c4 * 4 + (l >> 4)] = v;
        }
    } else {
        // cvec: c[j] = b2 . W_fc[:,j]
        float v[5];
        #pragma unroll
        for (int j = 0; j < 5; j++) v[j] = b2[t] * W_fc[t * 5 + j];
        #pragma unroll
        for (int off = 1; off < 64; off <<= 1)
            #pragma unroll
            for (int j = 0; j < 5; j++) v[j] += __shfl_xor(v[j], off);
        int w = t >> 6, l = t & 63;
        if (l == 0) { for (int j = 0; j < 5; j++) red[w][j] = v[j]; }
        __syncthreads();
        if (t == 0)
            for (int j = 0; j < 5; j++) cvec[j] = red[0][j] + red[1][j] + red[2][j] + red[3][j];
    }
}

// ---- GAT1 attention: 2 query rows per block (256 blocks) ----
__global__ __launch_bounds__(256) void k_gat1_attn(
    const int* __restrict__ adj, const float* __restrict__ hp1,
    const float* __restrict__ ss1, const float* __restrict__ sd1,
    const float* __restrict__ b1, unsigned short* __restrict__ abf)
{
    __shared__ float p[2][H1][NP];   // 32 KB
    __shared__ float den[2][H1];
    int t = threadIdx.x;
    int n0 = blockIdx.x * 2;
    for (int rr = 0; rr < 32; rr++) {
        int idx = rr * 256 + t;       // i(1) h(3) m(9)
        int i = idx >> 12, h = (idx >> 9) & 7, m = idx & 511;
        float a = adj[(n0 + i) * NP + m] > 0 ? 1.0f : 0.0f;
        float e = ss1[h * NP + n0 + i] + sd1[h * NP + m];
        e = fmaxf(e, NEG * e);
        p[i][h][m] = a * __expf(e);
    }
    __syncthreads();
    int w = t >> 6, l = t & 63;
    {
        int i = w & 1;
        #pragma unroll
        for (int hh = 0; hh < 4; hh++) {
            int h = (w >> 1) * 4 + hh;
            float s = 0;
            #pragma unroll
            for (int q = 0; q < 8; q++) s += p[i][h][l + 64 * q];
            #pragma unroll
            for (int off = 1; off < 64; off <<= 1) s += __shfl_xor(s, off);
            if (l == 0) den[i][h] = s;
        }
    }
    __syncthreads();
    int h = t >> 5, o = t & 31;
    float acc[2] = {0, 0};
    #pragma unroll 4
    for (int m = 0; m < NP; m++) {
        float v = hp1[m * 256 + t];
        acc[0] += p[0][h][m] * v;
        acc[1] += p[1][h][m] * v;
    }
    float bo = b1[o];
    #pragma unroll
    for (int i = 0; i < 2; i++) {
        float r = acc[i] / den[i][h] + bo;
        r = r > 0.f ? r : expm1f(r);   // elu
        abf[(NW + n0 + i) * FIN + t] = f2bf(r);
    }
}

// ---- hp2 GEMM with FUSED ss2/sd2/G reduction epilogue ----
__global__ __launch_bounds__(256) void k_gemm_hp2(
    const unsigned short* __restrict__ abf, const unsigned short* __restrict__ btbf,
    const float* __restrict__ a_src2, const float* __restrict__ a_dst2,
    const float* __restrict__ W_fc, float* __restrict__ gpart)
{
    int bid = blockIdx.x;
    int h = bid >> 6;
    int rem = bid & 63;
    int mt = rem >> 1, nt = rem & 1;
    int w = threadIdx.x >> 6, l = threadIdx.x & 63;
    int m0 = mt * 128 + (w >> 1) * 64;
    int n0 = nt * 128 + (w & 1) * 64;
    int lr = l & 15, lq = l >> 4;
    const unsigned short* bbase = btbf + h * O2 * FIN;
    f32x4 acc[4][4];
    #pragma unroll
    for (int i = 0; i < 4; i++)
        #pragma unroll
        for (int j = 0; j < 4; j++) acc[i][j] = (f32x4){0.f, 0.f, 0.f, 0.f};
    for (int k = 0; k < FIN; k += 32) {
        bf16x8 a[4], b[4];
        int kc = k + lq * 8;
        #pragma unroll
        for (int i = 0; i < 4; i++)
            a[i] = *(const bf16x8*)(abf + (m0 + i * 16 + lr) * FIN + kc);
        #pragma unroll
        for (int j = 0; j < 4; j++)
            b[j] = *(const bf16x8*)(bbase + (n0 + j * 16 + lr) * FIN + kc);
        #pragma unroll
        for (int i = 0; i < 4; i++)
            #pragma unroll
            for (int j = 0; j < 4; j++)
                acc[i][j] = __builtin_amdgcn_mfma_f32_16x16x32_bf16(a[i], b[j], acc[i][j], 0, 0, 0);
    }
    int slice = nt * 2 + (w & 1);
    float as[4], ad[4], wfc[4][5];
    #pragma unroll
    for (int j = 0; j < 4; j++) {
        int col = n0 + j * 16 + lr;
        as[j] = a_src2[h * O2 + col];
        ad[j] = a_dst2[h * O2 + col];
        #pragma unroll
        for (int jj = 0; jj < 5; jj++) wfc[j][jj] = W_fc[col * 5 + jj];
    }
    float* base = gpart + ((size_t)h * 4 + slice) * NT * 8;
    #pragma unroll
    for (int i = 0; i < 4; i++) {
        #pragma unroll
        for (int r = 0; r < 4; r++) {
            float s[7] = {0,0,0,0,0,0,0};
            #pragma unroll
            for (int j = 0; j < 4; j++) {
                float x = acc[i][j][r];
                float th = fast_tanh(x);
                s[0] += th * as[j];
                s[1] += th * ad[j];
                #pragma unroll
                for (int jj = 0; jj < 5; jj++) s[2 + jj] += x * wfc[j][jj];
            }
            #pragma unroll
            for (int off = 1; off < 16; off <<= 1)
                #pragma unroll
                for (int q = 0; q < 7; q++) s[q] += __shfl_xor(s[q], off);
            if (lr == 0) {
                int m = m0 + i * 16 + lq * 4 + r;
                float* dst = base + (size_t)m * 8;
                #pragma unroll
                for (int q = 0; q < 7; q++) dst[q] = s[q];
            }
        }
    }
}

// ---- combine slices -> Etab/Eptab (query side) + T={F,Fp,1,g0,g1,g2,g3,g4} (key side) ----
__global__ __launch_bounds__(256) void k_comb_hp2(
    const float* __restrict__ gpart,
    float* __restrict__ Etab, float* __restrict__ Eptab, float* __restrict__ T)
{
    int idx = blockIdx.x * 256 + threadIdx.x;   // h*NT + m
    float s[7] = {0,0,0,0,0,0,0};
    #pragma unroll
    for (int sl = 0; sl < 4; sl++) {
        const float* p = gpart + (((size_t)(idx >> 12) * 4 + sl) * NT + (idx & (NT - 1))) * 8;
        #pragma unroll
        for (int q = 0; q < 7; q++) s[q] += p[q];
    }
    Etab[idx]  = __expf(s[0]);
    Eptab[idx] = __expf(NEG * s[0]);
    float4 t0 = {__expf(s[1]), __expf(NEG * s[1]), 1.0f, s[2]};
    float4 t1 = {s[3], s[4], s[5], s[6]};
    *(float4*)(T + (size_t)idx * 8)     = t0;
    *(float4*)(T + (size_t)idx * 8 + 4) = t1;
}

// ---- GAT2 attention: pk-f32 inner loop, exp-max identity, sgpr adjacency mask ----
// grid: nb(56) x h(8) x c(2), 512 thr; wave owns 8 rows; lane owns m = c*2048+q*64+l
__global__ __launch_bounds__(512) void k_gat2_attn(
    const u64* __restrict__ packed, const float* __restrict__ Etab,
    const float* __restrict__ Eptab, const float* __restrict__ T,
    float* __restrict__ part)
{
    int t = threadIdx.x;
    int w = t >> 6, l = t & 63;
    int b = blockIdx.x;
    int nb = b % 56;
    int h  = (b / 56) & 7;
    int c  = b / 448;
    int n0 = nb * 64 + w * 8;
    // (E, Ep) per row as a 64-bit sgpr pair (lo=E, hi=Ep)
    u64 epk[8];
    #pragma unroll
    for (int i = 0; i < 8; i++) {
        int r = h * NT + n0 + i;
        unsigned e  = __builtin_amdgcn_readfirstlane(__float_as_uint(Etab[r]));
        unsigned ep = __builtin_amdgcn_readfirstlane(__float_as_uint(Eptab[r]));
        epk[i] = ((u64)ep << 32) | e;
    }
    v2f accA[8], accB[8], accC[8];   // (den,num0) (num1,num2) (num3,num4)
    #pragma unroll
    for (int i = 0; i < 8; i++) {
        accA[i] = (v2f){0.f, 0.f}; accB[i] = (v2f){0.f, 0.f}; accC[i] = (v2f){0.f, 0.f};
    }
    const float* Th = T + ((size_t)h * NT + c * 2048) * 8;
    const u64* prow = packed + c * 32;
    for (int q = 0; q < 32; q++) {
        const float* tp = Th + (size_t)(q * 64 + l) * 8;
        f32x4 t0 = *(const f32x4*)tp;
        f32x4 t1 = *(const f32x4*)(tp + 4);
        v2f ffp = {t0.x, t0.y};          // (F, Fp)
        v2f g01 = {t0.z, t0.w};          // (1, g0)
        v2f g12 = {t1.x, t1.y};          // (g1, g2)
        v2f g34 = {t1.z, t1.w};          // (g3, g4)
        #pragma unroll
        for (int i = 0; i < 8; i++) {
            // wave-uniform adjacency word -> force into SGPR pair via readfirstlane
            u64 wv = prow[(size_t)(n0 + i) * 64 + q];
            unsigned wlo = __builtin_amdgcn_readfirstlane((unsigned)wv);
            unsigned whi = __builtin_amdgcn_readfirstlane((unsigned)(wv >> 32));
            u64 word = ((u64)whi << 32) | wlo;
            v2f pab;
            asm("v_pk_mul_f32 %0, %1, %2" : "=v"(pab) : "v"(ffp), "s"(epk[i]));
            float pp0 = fmaxf(pab.x, pab.y);              // exp(leaky(ss+sd))
            float pp;
            asm("v_cndmask_b32 %0, 0, %1, %2" : "=v"(pp) : "v"(pp0), "s"(word));
            v2f ppv; ppv.x = pp; ppv.y = pp;
            asm("v_pk_fma_f32 %0, %1, %2, %0" : "+v"(accA[i]) : "v"(ppv), "v"(g01));
            asm("v_pk_fma_f32 %0, %1, %2, %0" : "+v"(accB[i]) : "v"(ppv), "v"(g12));
            asm("v_pk_fma_f32 %0, %1, %2, %0" : "+v"(accC[i]) : "v"(ppv), "v"(g34));
        }
    }
    #pragma unroll
    for (int i = 0; i < 8; i++) {
        float v[6];
        v[0] = accA[i].x; v[1] = accA[i].y;
        v[2] = accB[i].x; v[3] = accB[i].y;
        v[4] = accC[i].x; v[5] = accC[i].y;
        #pragma unroll
        for (int off = 1; off < 64; off <<= 1)
            #pragma unroll
            for (int k = 0; k < 6; k++) v[k] += __shfl_xor(v[k], off);
        if (l == 0) {
            float* dst = part + (((size_t)c * NW + n0 + i) * 8 + h) * 6;
            #pragma unroll
            for (int k = 0; k < 6; k++) dst[k] = v[k];
        }
    }
}

// ---- combine chunks + heads -> hf[n][5] ----
__global__ __launch_bounds__(256) void k_gat2_comb(const float* __restrict__ part,
                                                   float* __restrict__ hf) {
    int idx = blockIdx.x * 256 + threadIdx.x;  // n*8 + h
    int n = idx >> 3, h = idx & 7;
    float den = 0, num[5] = {0,0,0,0,0};
    #pragma unroll
    for (int cc = 0; cc < 2; cc++) {
        const float* p = part + (((size_t)cc * NW + n) * 8 + h) * 6;
        den += p[0];
        #pragma unroll
        for (int j = 0; j < 5; j++) num[j] += p[1 + j];
    }
    float inv = 1.0f / (den * 8.0f);
    float v[5];
    #pragma unroll
    for (int j = 0; j < 5; j++) v[j] = num[j] * inv;
    #pragma unroll
    for (int off = 1; off < 8; off <<= 1)
        #pragma unroll
        for (int j = 0; j < 5; j++) v[j] += __shfl_xor(v[j], off);
    if (h == 0) {
        #pragma unroll
        for (int j = 0; j < 5; j++) hf[n * 5 + j] = v[j];
    }
}

// ---- out[b][j] = (input[b].hf[:,j]) / sum(input[b]) + c[j] + b_fc[j] ----
__global__ __launch_bounds__(256) void k_final(
    const float* __restrict__ input, const float* __restrict__ hf,
    const float* __restrict__ cvec, const float* __restrict__ b_fc,
    float* __restrict__ out)
{
    int b = blockIdx.x, t = threadIdx.x;
    const float4* row4 = (const float4*)(input + (size_t)b * NW);
    const float4* hf4 = (const float4*)hf;
    float s = 0.f, a[5] = {0.f, 0.f, 0.f, 0.f, 0.f};
    for (int idx = t; idx < NW / 4; idx += 256) {
        float4 x = row4[idx];
        float f[20];
        #pragma unroll
        for (int q = 0; q < 5; q++) *(float4*)(f + 4 * q) = hf4[idx * 5 + q];
        s += x.x + x.y + x.z + x.w;
        #pragma unroll
        for (int j = 0; j < 5; j++)
            a[j] += x.x * f[j] + x.y * f[5 + j] + x.z * f[10 + j] + x.w * f[15 + j];
    }
    #pragma unroll
    for (int off = 1; off < 64; off <<= 1) {
        s += __shfl_xor(s, off);
        #pragma unroll
        for (int j = 0; j < 5; j++) a[j] += __shfl_xor(a[j], off);
    }
    __shared__ float red[4][6];
    int w = t >> 6, l = t & 63;
    if (l == 0) { red[w][0] = s; for (int j = 0; j < 5; j++) red[w][j + 1] = a[j]; }
    __syncthreads();
    if (t < 5) {
        float st = red[0][0] + red[1][0] + red[2][0] + red[3][0];
        float aj = red[0][t + 1] + red[1][t + 1] + red[2][t + 1] + red[3][t + 1];
        out[b * 5 + t] = aj / st + cvec[t] + b_fc[t];
    }
}

extern "C" void kernel_launch(void* const* d_in, const int* in_sizes, int n_in,
                              void* d_out, int out_size, void* d_ws, size_t ws_size,
                              hipStream_t stream) {
    const float* input   = (const float*)d_in[0];
    const float* pf      = (const float*)d_in[1];
    const float* wf      = (const float*)d_in[2];
    const float* w1      = (const float*)d_in[3];
    const float* a_src1  = (const float*)d_in[4];
    const float* a_dst1  = (const float*)d_in[5];
    const float* b1      = (const float*)d_in[6];
    const float* w2      = (const float*)d_in[7];
    const float* a_src2  = (const float*)d_in[8];
    const float* a_dst2  = (const float*)d_in[9];
    const float* b2      = (const float*)d_in[10];
    const float* W_fc    = (const float*)d_in[11];
    const float* b_fc    = (const float*)d_in[12];
    const int* pern_adj  = (const int*)d_in[13];
    const int* wp_adj    = (const int*)d_in[14];
    float* out = (float*)d_out;

    char* ws = (char*)d_ws;
    unsigned short* abf    = (unsigned short*)(ws);            // 2 MB
    unsigned short* btbf   = (unsigned short*)(ws + 2097152);  // 1 MB
    float*          hp1    = (float*)(ws + 3145728);           // 512 KB
    float*          ss1    = (float*)(ws + 3670016);           // 16 KB
    float*          sd1    = (float*)(ws + 3686400);           // 16 KB
    float*          Etab   = (float*)(ws + 3833856);           // 128 KB
    float*          Eptab  = (float*)(ws + 3964928);           // 128 KB
    float*          T      = (float*)(ws + 4096000);           // 1 MB
    float*          hf     = (float*)(ws + 5144576);           // 70 KB
    float*          cvec   = (float*)(ws + 5216256);           // 64 B
    u64*            packed = (u64*)(ws + 5216512);             // 1.75 MB
    float*          gpart  = (float*)(ws + 7051520);           // 4 MB
    float*          part   = (float*)(ws + 11245824);          // 1.4 MB

    k_prep<<<6785, 256, 0, stream>>>(wf, pf, w1, a_src1, a_dst1, w2, b2, W_fc,
                                     wp_adj, abf, btbf, hp1, ss1, sd1, packed, cvec);
    k_gat1_attn<<<256, 256, 0, stream>>>(pern_adj, hp1, ss1, sd1, b1, abf);
    k_gemm_hp2<<<512, 256, 0, stream>>>(abf, btbf, a_src2, a_dst2, W_fc, gpart);
    k_comb_hp2<<<128, 256, 0, stream>>>(gpart, Etab, Eptab, T);
    k_gat2_attn<<<896, 512, 0, stream>>>(packed, Etab, Eptab, T, part);
    k_gat2_comb<<<112, 256, 0, stream>>>(part, hf);
    k_final<<<1024, 256, 0, stream>>>(input, hf, cvec, b_fc, out);
}

// Round 7
// 283.191 us; speedup vs baseline: 1.1088x; 1.1088x over previous
//
#include <hip/hip_runtime.h>
#include <hip/hip_bf16.h>
#include <math.h>

#define NP 512
#define NW 3584
#define NT 4096
#define FIN 256
#define H1 8
#define O1 32
#define H2 8
#define O2 256
#define NEG 0.2f

typedef __attribute__((ext_vector_type(8))) short bf16x8;
typedef __attribute__((ext_vector_type(4))) float f32x4;
typedef __attribute__((ext_vector_type(2))) float v2f;
typedef unsigned long long u64;

__device__ __forceinline__ unsigned short f2bf(float f) {
    unsigned u = __float_as_uint(f);
    unsigned r = (u + 0x7FFF + ((u >> 16) & 1)) >> 16;
    return (unsigned short)r;
}

__device__ __forceinline__ float fast_tanh(float x) {
    float ex = __expf(2.0f * x);
    return 1.0f - 2.0f / (ex + 1.0f);   // saturates to +-1
}

// ================= fused prep: conv_word | gat1_hp | conv_w2 | pack_adj | cvec ========
// grid = 3584 + 256 + 2048 + 896 + 1 = 6785 blocks of 256
__global__ __launch_bounds__(256) void k_prep(
    const float* __restrict__ wf, const float* __restrict__ pf,
    const float* __restrict__ w1, const float* __restrict__ a_src1,
    const float* __restrict__ a_dst1, const float* __restrict__ w2,
    const float* __restrict__ b2, const float* __restrict__ W_fc,
    const int* __restrict__ wp_adj,
    unsigned short* __restrict__ abf, unsigned short* __restrict__ btbf,
    float* __restrict__ hp1, float* __restrict__ ss1, float* __restrict__ sd1,
    u64* __restrict__ packed, float* __restrict__ cvec)
{
    __shared__ float feat[2][FIN];
    __shared__ float red[4][5];
    int blk = blockIdx.x;
    int t = threadIdx.x;
    if (blk < 3584) {
        // conv_word
        int i = blk * 256 + t;
        abf[i] = f2bf(wf[i]);
    } else if (blk < 3840) {
        // gat1_hp: 2 rows per block
        int n0 = (blk - 3584) * 2;
        feat[0][t] = pf[n0 * FIN + t];
        feat[1][t] = pf[(n0 + 1) * FIN + t];
        __syncthreads();
        int h = t >> 5, o = t & 31;
        float acc0 = 0.f, acc1 = 0.f;
        const float* wcol = w1 + h * FIN * O1 + o;
        #pragma unroll 4
        for (int f = 0; f < FIN; f++) {
            float w = wcol[f * O1];
            acc0 += feat[0][f] * w;
            acc1 += feat[1][f] * w;
        }
        hp1[n0 * 256 + t] = acc0;
        hp1[(n0 + 1) * 256 + t] = acc1;
        float as = a_src1[h * O1 + o];
        float ad = a_dst1[h * O1 + o];
        float accs[2] = {acc0, acc1};
        #pragma unroll
        for (int i = 0; i < 2; i++) {
            float th = tanhf(accs[i]);
            float vs = th * as, vd = th * ad;
            #pragma unroll
            for (int off = 1; off < 32; off <<= 1) {
                vs += __shfl_xor(vs, off);
                vd += __shfl_xor(vd, off);
            }
            if (o == 0) { ss1[h * NP + n0 + i] = vs; sd1[h * NP + n0 + i] = vd; }
        }
    } else if (blk < 5888) {
        // conv_w2: [h][f][o] -> bf16 [h][o][f]
        int idx = (blk - 3840) * 256 + t;
        int f = idx & 255, o = (idx >> 8) & 255, h = idx >> 16;
        btbf[idx] = f2bf(w2[(h * FIN + f) * O2 + o]);
    } else if (blk < 6784) {
        // pack_adj
        int w = t >> 6, l = t & 63;
        int r = (blk - 5888) * 4 + w;
        const int4* row = (const int4*)(wp_adj + (size_t)r * NT);
        for (int c4 = 0; c4 < 16; c4++) {
            int4 x = row[c4 * 64 + l];
            u64 nib = (u64)((x.x != 0 ? 1 : 0) | (x.y != 0 ? 2 : 0) |
                            (x.z != 0 ? 4 : 0) | (x.w != 0 ? 8 : 0));
            u64 v = nib << (4 * (l & 15));
            v |= __shfl_xor(v, 1);
            v |= __shfl_xor(v, 2);
            v |= __shfl_xor(v, 4);
            v |= __shfl_xor(v, 8);
            if ((l & 15) == 0) packed[(size_t)r * 64 + c4 * 4 + (l >> 4)] = v;
        }
    } else {
        // cvec: c[j] = b2 . W_fc[:,j]
        float v[5];
        #pragma unroll
        for (int j = 0; j < 5; j++) v[j] = b2[t] * W_fc[t * 5 + j];
        #pragma unroll
        for (int off = 1; off < 64; off <<= 1)
            #pragma unroll
            for (int j = 0; j < 5; j++) v[j] += __shfl_xor(v[j], off);
        int w = t >> 6, l = t & 63;
        if (l == 0) { for (int j = 0; j < 5; j++) red[w][j] = v[j]; }
        __syncthreads();
        if (t == 0)
            for (int j = 0; j < 5; j++) cvec[j] = red[0][j] + red[1][j] + red[2][j] + red[3][j];
    }
}

// ---- GAT1 attention: 2 query rows per block (256 blocks) ----
__global__ __launch_bounds__(256) void k_gat1_attn(
    const int* __restrict__ adj, const float* __restrict__ hp1,
    const float* __restrict__ ss1, const float* __restrict__ sd1,
    const float* __restrict__ b1, unsigned short* __restrict__ abf)
{
    __shared__ float p[2][H1][NP];   // 32 KB
    __shared__ float den[2][H1];
    int t = threadIdx.x;
    int n0 = blockIdx.x * 2;
    for (int rr = 0; rr < 32; rr++) {
        int idx = rr * 256 + t;       // i(1) h(3) m(9)
        int i = idx >> 12, h = (idx >> 9) & 7, m = idx & 511;
        float a = adj[(n0 + i) * NP + m] > 0 ? 1.0f : 0.0f;
        float e = ss1[h * NP + n0 + i] + sd1[h * NP + m];
        e = fmaxf(e, NEG * e);
        p[i][h][m] = a * __expf(e);
    }
    __syncthreads();
    int w = t >> 6, l = t & 63;
    {
        int i = w & 1;
        #pragma unroll
        for (int hh = 0; hh < 4; hh++) {
            int h = (w >> 1) * 4 + hh;
            float s = 0;
            #pragma unroll
            for (int q = 0; q < 8; q++) s += p[i][h][l + 64 * q];
            #pragma unroll
            for (int off = 1; off < 64; off <<= 1) s += __shfl_xor(s, off);
            if (l == 0) den[i][h] = s;
        }
    }
    __syncthreads();
    int h = t >> 5, o = t & 31;
    float acc[2] = {0, 0};
    #pragma unroll 4
    for (int m = 0; m < NP; m++) {
        float v = hp1[m * 256 + t];
        acc[0] += p[0][h][m] * v;
        acc[1] += p[1][h][m] * v;
    }
    float bo = b1[o];
    #pragma unroll
    for (int i = 0; i < 2; i++) {
        float r = acc[i] / den[i][h] + bo;
        r = r > 0.f ? r : expm1f(r);   // elu
        abf[(NW + n0 + i) * FIN + t] = f2bf(r);
    }
}

// ---- hp2 GEMM with FUSED ss2/sd2/G reduction epilogue ----
__global__ __launch_bounds__(256) void k_gemm_hp2(
    const unsigned short* __restrict__ abf, const unsigned short* __restrict__ btbf,
    const float* __restrict__ a_src2, const float* __restrict__ a_dst2,
    const float* __restrict__ W_fc, float* __restrict__ gpart)
{
    int bid = blockIdx.x;
    int h = bid >> 6;
    int rem = bid & 63;
    int mt = rem >> 1, nt = rem & 1;
    int w = threadIdx.x >> 6, l = threadIdx.x & 63;
    int m0 = mt * 128 + (w >> 1) * 64;
    int n0 = nt * 128 + (w & 1) * 64;
    int lr = l & 15, lq = l >> 4;
    const unsigned short* bbase = btbf + h * O2 * FIN;
    f32x4 acc[4][4];
    #pragma unroll
    for (int i = 0; i < 4; i++)
        #pragma unroll
        for (int j = 0; j < 4; j++) acc[i][j] = (f32x4){0.f, 0.f, 0.f, 0.f};
    for (int k = 0; k < FIN; k += 32) {
        bf16x8 a[4], b[4];
        int kc = k + lq * 8;
        #pragma unroll
        for (int i = 0; i < 4; i++)
            a[i] = *(const bf16x8*)(abf + (m0 + i * 16 + lr) * FIN + kc);
        #pragma unroll
        for (int j = 0; j < 4; j++)
            b[j] = *(const bf16x8*)(bbase + (n0 + j * 16 + lr) * FIN + kc);
        #pragma unroll
        for (int i = 0; i < 4; i++)
            #pragma unroll
            for (int j = 0; j < 4; j++)
                acc[i][j] = __builtin_amdgcn_mfma_f32_16x16x32_bf16(a[i], b[j], acc[i][j], 0, 0, 0);
    }
    int slice = nt * 2 + (w & 1);
    float as[4], ad[4], wfc[4][5];
    #pragma unroll
    for (int j = 0; j < 4; j++) {
        int col = n0 + j * 16 + lr;
        as[j] = a_src2[h * O2 + col];
        ad[j] = a_dst2[h * O2 + col];
        #pragma unroll
        for (int jj = 0; jj < 5; jj++) wfc[j][jj] = W_fc[col * 5 + jj];
    }
    float* base = gpart + ((size_t)h * 4 + slice) * NT * 8;
    #pragma unroll
    for (int i = 0; i < 4; i++) {
        #pragma unroll
        for (int r = 0; r < 4; r++) {
            float s[7] = {0,0,0,0,0,0,0};
            #pragma unroll
            for (int j = 0; j < 4; j++) {
                float x = acc[i][j][r];
                float th = fast_tanh(x);
                s[0] += th * as[j];
                s[1] += th * ad[j];
                #pragma unroll
                for (int jj = 0; jj < 5; jj++) s[2 + jj] += x * wfc[j][jj];
            }
            #pragma unroll
            for (int off = 1; off < 16; off <<= 1)
                #pragma unroll
                for (int q = 0; q < 7; q++) s[q] += __shfl_xor(s[q], off);
            if (lr == 0) {
                int m = m0 + i * 16 + lq * 4 + r;
                float* dst = base + (size_t)m * 8;
                #pragma unroll
                for (int q = 0; q < 7; q++) dst[q] = s[q];
            }
        }
    }
}

// ---- combine slices -> Etab/Eptab (query side) + T={F,Fp,1,g0,g1,g2,g3,g4} (key side) ----
__global__ __launch_bounds__(256) void k_comb_hp2(
    const float* __restrict__ gpart,
    float* __restrict__ Etab, float* __restrict__ Eptab, float* __restrict__ T)
{
    int idx = blockIdx.x * 256 + threadIdx.x;   // h*NT + m
    float s[7] = {0,0,0,0,0,0,0};
    #pragma unroll
    for (int sl = 0; sl < 4; sl++) {
        const float* p = gpart + (((size_t)(idx >> 12) * 4 + sl) * NT + (idx & (NT - 1))) * 8;
        #pragma unroll
        for (int q = 0; q < 7; q++) s[q] += p[q];
    }
    Etab[idx]  = __expf(s[0]);
    Eptab[idx] = __expf(NEG * s[0]);
    float4 t0 = {__expf(s[1]), __expf(NEG * s[1]), 1.0f, s[2]};
    float4 t1 = {s[3], s[4], s[5], s[6]};
    *(float4*)(T + (size_t)idx * 8)     = t0;
    *(float4*)(T + (size_t)idx * 8 + 4) = t1;
}

// ---- GAT2 attention: LDS-staged u32 bitmask + bfe/cvt mask, pk-f32 accumulation ----
// grid: nb(56) x h(8) x c(2), 512 thr; wave owns 8 rows; lane owns m = c*2048+q*64+l
__global__ __launch_bounds__(512) void k_gat2_attn(
    const u64* __restrict__ packed, const float* __restrict__ Etab,
    const float* __restrict__ Eptab, const float* __restrict__ T,
    float* __restrict__ part)
{
    __shared__ unsigned pw[64 * 64];   // 16 KB: [row][u32 word], 64 words per row-chunk
    int t = threadIdx.x;
    int w = t >> 6, l = t & 63;
    int b = blockIdx.x;
    int nb = b % 56;
    int h  = (b / 56) & 7;
    int c  = b / 448;
    int rbase = nb * 64;
    // stage adjacency words for this (row-block, c): 64 rows x 64 u32
    const unsigned* p32 = (const unsigned*)packed;   // row stride 128 u32
    #pragma unroll
    for (int u = 0; u < 8; u++) {
        int idx = u * 512 + t;          // 4096 words
        int row = idx >> 6, word = idx & 63;
        pw[idx] = p32[(size_t)(rbase + row) * 128 + c * 64 + word];
    }
    __syncthreads();
    int n0 = rbase + w * 8;             // this wave's 8 query rows
    // (E, Ep) per row as a 64-bit sgpr pair (lo=E, hi=Ep)
    u64 epk[8];
    #pragma unroll
    for (int i = 0; i < 8; i++) {
        int r = h * NT + n0 + i;
        unsigned e  = __builtin_amdgcn_readfirstlane(__float_as_uint(Etab[r]));
        unsigned ep = __builtin_amdgcn_readfirstlane(__float_as_uint(Eptab[r]));
        epk[i] = ((u64)ep << 32) | e;
    }
    v2f accA[8], accB[8], accC[8];   // (den,num0) (num1,num2) (num3,num4)
    #pragma unroll
    for (int i = 0; i < 8; i++) {
        accA[i] = (v2f){0.f, 0.f}; accB[i] = (v2f){0.f, 0.f}; accC[i] = (v2f){0.f, 0.f};
    }
    const float* Th = T + ((size_t)h * NT + c * 2048) * 8;
    const unsigned* wbase = pw + w * 512 + (l >> 5);   // + i*64 + q*2 (imm offsets)
    int lsh = l & 31;
    for (int q = 0; q < 32; q++) {
        const float* tp = Th + (size_t)(q * 64 + l) * 8;
        f32x4 t0 = *(const f32x4*)tp;
        f32x4 t1 = *(const f32x4*)(tp + 4);
        v2f ffp = {t0.x, t0.y};          // (F, Fp)
        v2f g01 = {t0.z, t0.w};          // (1, g0)
        v2f g12 = {t1.x, t1.y};          // (g1, g2)
        v2f g34 = {t1.z, t1.w};          // (g3, g4)
        #pragma unroll
        for (int i = 0; i < 8; i++) {
            unsigned word = wbase[i * 64 + q * 2];    // ds_read_b32, imm offset
            float bm = (float)((word >> lsh) & 1u);   // v_bfe + v_cvt
            v2f pab;
            asm("v_pk_mul_f32 %0, %1, %2" : "=v"(pab) : "v"(ffp), "s"(epk[i]));
            float pp = fmaxf(pab.x, pab.y) * bm;      // exp(leaky(ss+sd)) * adj
            v2f ppv; ppv.x = pp; ppv.y = pp;
            asm("v_pk_fma_f32 %0, %1, %2, %0" : "+v"(accA[i]) : "v"(ppv), "v"(g01));
            asm("v_pk_fma_f32 %0, %1, %2, %0" : "+v"(accB[i]) : "v"(ppv), "v"(g12));
            asm("v_pk_fma_f32 %0, %1, %2, %0" : "+v"(accC[i]) : "v"(ppv), "v"(g34));
        }
    }
    #pragma unroll
    for (int i = 0; i < 8; i++) {
        float v[6];
        v[0] = accA[i].x; v[1] = accA[i].y;
        v[2] = accB[i].x; v[3] = accB[i].y;
        v[4] = accC[i].x; v[5] = accC[i].y;
        #pragma unroll
        for (int off = 1; off < 64; off <<= 1)
            #pragma unroll
            for (int k = 0; k < 6; k++) v[k] += __shfl_xor(v[k], off);
        if (l == 0) {
            float* dst = part + (((size_t)c * NW + n0 + i) * 8 + h) * 6;
            #pragma unroll
            for (int k = 0; k < 6; k++) dst[k] = v[k];
        }
    }
}

// ---- combine chunks + heads -> hf[n][5] ----
__global__ __launch_bounds__(256) void k_gat2_comb(const float* __restrict__ part,
                                                   float* __restrict__ hf) {
    int idx = blockIdx.x * 256 + threadIdx.x;  // n*8 + h
    int n = idx >> 3, h = idx & 7;
    float den = 0, num[5] = {0,0,0,0,0};
    #pragma unroll
    for (int cc = 0; cc < 2; cc++) {
        const float* p = part + (((size_t)cc * NW + n) * 8 + h) * 6;
        den += p[0];
        #pragma unroll
        for (int j = 0; j < 5; j++) num[j] += p[1 + j];
    }
    float inv = 1.0f / (den * 8.0f);
    float v[5];
    #pragma unroll
    for (int j = 0; j < 5; j++) v[j] = num[j] * inv;
    #pragma unroll
    for (int off = 1; off < 8; off <<= 1)
        #pragma unroll
        for (int j = 0; j < 5; j++) v[j] += __shfl_xor(v[j], off);
    if (h == 0) {
        #pragma unroll
        for (int j = 0; j < 5; j++) hf[n * 5 + j] = v[j];
    }
}

// ---- out[b][j] = (input[b].hf[:,j]) / sum(input[b]) + c[j] + b_fc[j] ----
__global__ __launch_bounds__(256) void k_final(
    const float* __restrict__ input, const float* __restrict__ hf,
    const float* __restrict__ cvec, const float* __restrict__ b_fc,
    float* __restrict__ out)
{
    int b = blockIdx.x, t = threadIdx.x;
    const float4* row4 = (const float4*)(input + (size_t)b * NW);
    const float4* hf4 = (const float4*)hf;
    float s = 0.f, a[5] = {0.f, 0.f, 0.f, 0.f, 0.f};
    for (int idx = t; idx < NW / 4; idx += 256) {
        float4 x = row4[idx];
        float f[20];
        #pragma unroll
        for (int q = 0; q < 5; q++) *(float4*)(f + 4 * q) = hf4[idx * 5 + q];
        s += x.x + x.y + x.z + x.w;
        #pragma unroll
        for (int j = 0; j < 5; j++)
            a[j] += x.x * f[j] + x.y * f[5 + j] + x.z * f[10 + j] + x.w * f[15 + j];
    }
    #pragma unroll
    for (int off = 1; off < 64; off <<= 1) {
        s += __shfl_xor(s, off);
        #pragma unroll
        for (int j = 0; j < 5; j++) a[j] += __shfl_xor(a[j], off);
    }
    __shared__ float red[4][6];
    int w = t >> 6, l = t & 63;
    if (l == 0) { red[w][0] = s; for (int j = 0; j < 5; j++) red[w][j + 1] = a[j]; }
    __syncthreads();
    if (t < 5) {
        float st = red[0][0] + red[1][0] + red[2][0] + red[3][0];
        float aj = red[0][t + 1] + red[1][t + 1] + red[2][t + 1] + red[3][t + 1];
        out[b * 5 + t] = aj / st + cvec[t] + b_fc[t];
    }
}

extern "C" void kernel_launch(void* const* d_in, const int* in_sizes, int n_in,
                              void* d_out, int out_size, void* d_ws, size_t ws_size,
                              hipStream_t stream) {
    const float* input   = (const float*)d_in[0];
    const float* pf      = (const float*)d_in[1];
    const float* wf      = (const float*)d_in[2];
    const float* w1      = (const float*)d_in[3];
    const float* a_src1  = (const float*)d_in[4];
    const float* a_dst1  = (const float*)d_in[5];
    const float* b1      = (const float*)d_in[6];
    const float* w2      = (const float*)d_in[7];
    const float* a_src2  = (const float*)d_in[8];
    const float* a_dst2  = (const float*)d_in[9];
    const float* b2      = (const float*)d_in[10];
    const float* W_fc    = (const float*)d_in[11];
    const float* b_fc    = (const float*)d_in[12];
    const int* pern_adj  = (const int*)d_in[13];
    const int* wp_adj    = (const int*)d_in[14];
    float* out = (float*)d_out;

    char* ws = (char*)d_ws;
    unsigned short* abf    = (unsigned short*)(ws);            // 2 MB
    unsigned short* btbf   = (unsigned short*)(ws + 2097152);  // 1 MB
    float*          hp1    = (float*)(ws + 3145728);           // 512 KB
    float*          ss1    = (float*)(ws + 3670016);           // 16 KB
    float*          sd1    = (float*)(ws + 3686400);           // 16 KB
    float*          Etab   = (float*)(ws + 3833856);           // 128 KB
    float*          Eptab  = (float*)(ws + 3964928);           // 128 KB
    float*          T      = (float*)(ws + 4096000);           // 1 MB
    float*          hf     = (float*)(ws + 5144576);           // 70 KB
    float*          cvec   = (float*)(ws + 5216256);           // 64 B
    u64*            packed = (u64*)(ws + 5216512);             // 1.75 MB
    float*          gpart  = (float*)(ws + 7051520);           // 4 MB
    float*          part   = (float*)(ws + 11245824);          // 1.4 MB

    k_prep<<<6785, 256, 0, stream>>>(wf, pf, w1, a_src1, a_dst1, w2, b2, W_fc,
                                     wp_adj, abf, btbf, hp1, ss1, sd1, packed, cvec);
    k_gat1_attn<<<256, 256, 0, stream>>>(pern_adj, hp1, ss1, sd1, b1, abf);
    k_gemm_hp2<<<512, 256, 0, stream>>>(abf, btbf, a_src2, a_dst2, W_fc, gpart);
    k_comb_hp2<<<128, 256, 0, stream>>>(gpart, Etab, Eptab, T);
    k_gat2_attn<<<896, 512, 0, stream>>>(packed, Etab, Eptab, T, part);
    k_gat2_comb<<<112, 256, 0, stream>>>(part, hf);
    k_final<<<1024, 256, 0, stream>>>(input, hf, cvec, b_fc, out);
}

// Round 8
// 281.872 us; speedup vs baseline: 1.1140x; 1.0047x over previous
//
#include <hip/hip_runtime.h>
#include <hip/hip_bf16.h>
#include <math.h>

#define NP 512
#define NW 3584
#define NT 4096
#define FIN 256
#define H1 8
#define O1 32
#define H2 8
#define O2 256
#define NEG 0.2f

typedef __attribute__((ext_vector_type(8))) short bf16x8;
typedef __attribute__((ext_vector_type(4))) float f32x4;
typedef __attribute__((ext_vector_type(2))) float v2f;
typedef unsigned long long u64;

__device__ __forceinline__ unsigned short f2bf(float f) {
    unsigned u = __float_as_uint(f);
    unsigned r = (u + 0x7FFF + ((u >> 16) & 1)) >> 16;
    return (unsigned short)r;
}

__device__ __forceinline__ float fast_tanh(float x) {
    float ex = __expf(2.0f * x);
    return 1.0f - 2.0f / (ex + 1.0f);   // saturates to +-1
}

// ===== fused prep: conv_word | gat1_hp | conv_w2(transpose) | pack_adj(transposed) | cvec
// grid = 896 + 256 + 128 + 896 + 1 = 2177 blocks of 256
__global__ __launch_bounds__(256) void k_prep(
    const float* __restrict__ wf, const float* __restrict__ pf,
    const float* __restrict__ w1, const float* __restrict__ a_src1,
    const float* __restrict__ a_dst1, const float* __restrict__ w2,
    const float* __restrict__ b2, const float* __restrict__ W_fc,
    const int* __restrict__ wp_adj,
    unsigned short* __restrict__ abf, unsigned short* __restrict__ btbf,
    float* __restrict__ hp1, float* __restrict__ ss1, float* __restrict__ sd1,
    unsigned* __restrict__ maskT, float* __restrict__ cvec)
{
    __shared__ float tile[64][65];   // 16.6 KB (conv_w2 transpose)
    __shared__ float feat[2][FIN];
    __shared__ float red[4][5];
    int blk = blockIdx.x;
    int t = threadIdx.x;
    if (blk < 896) {
        // conv_word: float4 -> ushort4
        int idx4 = blk * 256 + t;
        float4 x = ((const float4*)wf)[idx4];
        ushort4 y;
        y.x = f2bf(x.x); y.y = f2bf(x.y); y.z = f2bf(x.z); y.w = f2bf(x.w);
        ((ushort4*)abf)[idx4] = y;
    } else if (blk < 1152) {
        // gat1_hp: 2 rows per block
        int n0 = (blk - 896) * 2;
        feat[0][t] = pf[n0 * FIN + t];
        feat[1][t] = pf[(n0 + 1) * FIN + t];
        __syncthreads();
        int h = t >> 5, o = t & 31;
        float acc0 = 0.f, acc1 = 0.f;
        const float* wcol = w1 + h * FIN * O1 + o;
        #pragma unroll 4
        for (int f = 0; f < FIN; f++) {
            float w = wcol[f * O1];
            acc0 += feat[0][f] * w;
            acc1 += feat[1][f] * w;
        }
        hp1[n0 * 256 + t] = acc0;
        hp1[(n0 + 1) * 256 + t] = acc1;
        float as = a_src1[h * O1 + o];
        float ad = a_dst1[h * O1 + o];
        float accs[2] = {acc0, acc1};
        #pragma unroll
        for (int i = 0; i < 2; i++) {
            float th = tanhf(accs[i]);
            float vs = th * as, vd = th * ad;
            #pragma unroll
            for (int off = 1; off < 32; off <<= 1) {
                vs += __shfl_xor(vs, off);
                vd += __shfl_xor(vd, off);
            }
            if (o == 0) { ss1[h * NP + n0 + i] = vs; sd1[h * NP + n0 + i] = vd; }
        }
    } else if (blk < 1280) {
        // conv_w2: LDS-tiled transpose [h][f][o] -> bf16 [h][o][f], coalesced both ways
        int blk2 = blk - 1152;
        int h = blk2 >> 4;
        int f0 = ((blk2 >> 2) & 3) * 64;
        int o0 = (blk2 & 3) * 64;
        #pragma unroll
        for (int rr = 0; rr < 16; rr++) {
            int f = rr * 4 + (t >> 6);
            int o = t & 63;
            tile[f][o] = w2[((size_t)(h * FIN + f0 + f)) * O2 + o0 + o];
        }
        __syncthreads();
        #pragma unroll
        for (int rr = 0; rr < 16; rr++) {
            int o = rr * 4 + (t >> 6);
            int f = t & 63;
            btbf[((size_t)(h * O2 + o0 + o)) * FIN + f0 + f] = f2bf(tile[f][o]);
        }
    } else if (blk < 2176) {
        // pack_adj -> TRANSPOSED u32 layout: maskT[wd(128)][row(3584)]
        int w = t >> 6, l = t & 63;
        int r = (blk - 1280) * 4 + w;
        const int4* row = (const int4*)(wp_adj + (size_t)r * NT);
        for (int c4 = 0; c4 < 16; c4++) {
            int4 x = row[c4 * 64 + l];
            u64 nib = (u64)((x.x != 0 ? 1 : 0) | (x.y != 0 ? 2 : 0) |
                            (x.z != 0 ? 4 : 0) | (x.w != 0 ? 8 : 0));
            u64 v = nib << (4 * (l & 15));
            v |= __shfl_xor(v, 1);
            v |= __shfl_xor(v, 2);
            v |= __shfl_xor(v, 4);
            v |= __shfl_xor(v, 8);
            if ((l & 15) == 0) {
                int qw = c4 * 4 + (l >> 4);    // u64 index 0..63 (columns qw*64..+63)
                maskT[(size_t)(2 * qw) * NW + r]     = (unsigned)v;
                maskT[(size_t)(2 * qw + 1) * NW + r] = (unsigned)(v >> 32);
            }
        }
    } else {
        // cvec: c[j] = b2 . W_fc[:,j]
        float v[5];
        #pragma unroll
        for (int j = 0; j < 5; j++) v[j] = b2[t] * W_fc[t * 5 + j];
        #pragma unroll
        for (int off = 1; off < 64; off <<= 1)
            #pragma unroll
            for (int j = 0; j < 5; j++) v[j] += __shfl_xor(v[j], off);
        int w = t >> 6, l = t & 63;
        if (l == 0) { for (int j = 0; j < 5; j++) red[w][j] = v[j]; }
        __syncthreads();
        if (t == 0)
            for (int j = 0; j < 5; j++) cvec[j] = red[0][j] + red[1][j] + red[2][j] + red[3][j];
    }
}

// ---- GAT1 attention: 2 query rows per block (256 blocks) ----
__global__ __launch_bounds__(256) void k_gat1_attn(
    const int* __restrict__ adj, const float* __restrict__ hp1,
    const float* __restrict__ ss1, const float* __restrict__ sd1,
    const float* __restrict__ b1, unsigned short* __restrict__ abf)
{
    __shared__ float p[2][H1][NP];   // 32 KB
    __shared__ float den[2][H1];
    int t = threadIdx.x;
    int n0 = blockIdx.x * 2;
    for (int rr = 0; rr < 32; rr++) {
        int idx = rr * 256 + t;       // i(1) h(3) m(9)
        int i = idx >> 12, h = (idx >> 9) & 7, m = idx & 511;
        float a = adj[(n0 + i) * NP + m] > 0 ? 1.0f : 0.0f;
        float e = ss1[h * NP + n0 + i] + sd1[h * NP + m];
        e = fmaxf(e, NEG * e);
        p[i][h][m] = a * __expf(e);
    }
    __syncthreads();
    int w = t >> 6, l = t & 63;
    {
        int i = w & 1;
        #pragma unroll
        for (int hh = 0; hh < 4; hh++) {
            int h = (w >> 1) * 4 + hh;
            float s = 0;
            #pragma unroll
            for (int q = 0; q < 8; q++) s += p[i][h][l + 64 * q];
            #pragma unroll
            for (int off = 1; off < 64; off <<= 1) s += __shfl_xor(s, off);
            if (l == 0) den[i][h] = s;
        }
    }
    __syncthreads();
    int h = t >> 5, o = t & 31;
    float acc[2] = {0, 0};
    #pragma unroll 4
    for (int m = 0; m < NP; m++) {
        float v = hp1[m * 256 + t];
        acc[0] += p[0][h][m] * v;
        acc[1] += p[1][h][m] * v;
    }
    float bo = b1[o];
    #pragma unroll
    for (int i = 0; i < 2; i++) {
        float r = acc[i] / den[i][h] + bo;
        r = r > 0.f ? r : expm1f(r);   // elu
        abf[(NW + n0 + i) * FIN + t] = f2bf(r);
    }
}

// ---- hp2 GEMM with FUSED ss2/sd2/G reduction epilogue ----
__global__ __launch_bounds__(256) void k_gemm_hp2(
    const unsigned short* __restrict__ abf, const unsigned short* __restrict__ btbf,
    const float* __restrict__ a_src2, const float* __restrict__ a_dst2,
    const float* __restrict__ W_fc, float* __restrict__ gpart)
{
    int bid = blockIdx.x;
    int h = bid >> 6;
    int rem = bid & 63;
    int mt = rem >> 1, nt = rem & 1;
    int w = threadIdx.x >> 6, l = threadIdx.x & 63;
    int m0 = mt * 128 + (w >> 1) * 64;
    int n0 = nt * 128 + (w & 1) * 64;
    int lr = l & 15, lq = l >> 4;
    const unsigned short* bbase = btbf + h * O2 * FIN;
    f32x4 acc[4][4];
    #pragma unroll
    for (int i = 0; i < 4; i++)
        #pragma unroll
        for (int j = 0; j < 4; j++) acc[i][j] = (f32x4){0.f, 0.f, 0.f, 0.f};
    for (int k = 0; k < FIN; k += 32) {
        bf16x8 a[4], b[4];
        int kc = k + lq * 8;
        #pragma unroll
        for (int i = 0; i < 4; i++)
            a[i] = *(const bf16x8*)(abf + (m0 + i * 16 + lr) * FIN + kc);
        #pragma unroll
        for (int j = 0; j < 4; j++)
            b[j] = *(const bf16x8*)(bbase + (n0 + j * 16 + lr) * FIN + kc);
        #pragma unroll
        for (int i = 0; i < 4; i++)
            #pragma unroll
            for (int j = 0; j < 4; j++)
                acc[i][j] = __builtin_amdgcn_mfma_f32_16x16x32_bf16(a[i], b[j], acc[i][j], 0, 0, 0);
    }
    int slice = nt * 2 + (w & 1);
    float as[4], ad[4], wfc[4][5];
    #pragma unroll
    for (int j = 0; j < 4; j++) {
        int col = n0 + j * 16 + lr;
        as[j] = a_src2[h * O2 + col];
        ad[j] = a_dst2[h * O2 + col];
        #pragma unroll
        for (int jj = 0; jj < 5; jj++) wfc[j][jj] = W_fc[col * 5 + jj];
    }
    float* base = gpart + ((size_t)h * 4 + slice) * NT * 8;
    #pragma unroll
    for (int i = 0; i < 4; i++) {
        #pragma unroll
        for (int r = 0; r < 4; r++) {
            float s[7] = {0,0,0,0,0,0,0};
            #pragma unroll
            for (int j = 0; j < 4; j++) {
                float x = acc[i][j][r];
                float th = fast_tanh(x);
                s[0] += th * as[j];
                s[1] += th * ad[j];
                #pragma unroll
                for (int jj = 0; jj < 5; jj++) s[2 + jj] += x * wfc[j][jj];
            }
            #pragma unroll
            for (int off = 1; off < 16; off <<= 1)
                #pragma unroll
                for (int q = 0; q < 7; q++) s[q] += __shfl_xor(s[q], off);
            if (lr == 0) {
                int m = m0 + i * 16 + lq * 4 + r;
                float* dst = base + (size_t)m * 8;
                #pragma unroll
                for (int q = 0; q < 7; q++) dst[q] = s[q];
            }
        }
    }
}

// ---- combine slices -> Etab/Eptab (query side) + T={F,Fp,1,g0,g1,g2,g3,g4} (key side) ----
__global__ __launch_bounds__(256) void k_comb_hp2(
    const float* __restrict__ gpart,
    float* __restrict__ Etab, float* __restrict__ Eptab, float* __restrict__ T)
{
    int idx = blockIdx.x * 256 + threadIdx.x;   // h*NT + m
    float s[7] = {0,0,0,0,0,0,0};
    #pragma unroll
    for (int sl = 0; sl < 4; sl++) {
        const float* p = gpart + (((size_t)(idx >> 12) * 4 + sl) * NT + (idx & (NT - 1))) * 8;
        #pragma unroll
        for (int q = 0; q < 7; q++) s[q] += p[q];
    }
    Etab[idx]  = __expf(s[0]);
    Eptab[idx] = __expf(NEG * s[0]);
    float4 t0 = {__expf(s[1]), __expf(NEG * s[1]), 1.0f, s[2]};
    float4 t1 = {s[3], s[4], s[5], s[6]};
    *(float4*)(T + (size_t)idx * 8)     = t0;
    *(float4*)(T + (size_t)idx * 8 + 4) = t1;
}

// ---- GAT2 attention: transposed LDS mask (b128 reads), pk-f32, 3-step partial reduce ----
// grid: nb(56) x h(8) x c(2), 512 thr; wave owns 8 rows; lane owns m = c*2048+q*64+l
// part[(((c*NW+n)*8+h)*8+s)*8 + {den,num0..4,pad,pad}]
__global__ __launch_bounds__(512, 4) void k_gat2_attn(
    const unsigned* __restrict__ maskT, const float* __restrict__ Etab,
    const float* __restrict__ Eptab, const float* __restrict__ T,
    float* __restrict__ part)
{
    __shared__ unsigned pw[64 * 64];   // 16 KB: [wd 0..63][row 0..63]
    int t = threadIdx.x;
    int w = t >> 6, l = t & 63;
    int b = blockIdx.x;
    int nb = b % 56;
    int h  = (b / 56) & 7;
    int c  = b / 448;
    int rbase = nb * 64;
    // stage transposed mask words: coalesced (consecutive t = consecutive row)
    #pragma unroll
    for (int u = 0; u < 8; u++) {
        int idx = u * 512 + t;          // 4096 words
        int wd = idx >> 6, row = idx & 63;
        pw[idx] = maskT[(size_t)(c * 64 + wd) * NW + rbase + row];
    }
    __syncthreads();
    int n0 = rbase + w * 8;             // this wave's 8 query rows
    u64 epk[8];                          // (E, Ep) per row as sgpr pair
    #pragma unroll
    for (int i = 0; i < 8; i++) {
        int r = h * NT + n0 + i;
        unsigned e  = __builtin_amdgcn_readfirstlane(__float_as_uint(Etab[r]));
        unsigned ep = __builtin_amdgcn_readfirstlane(__float_as_uint(Eptab[r]));
        epk[i] = ((u64)ep << 32) | e;
    }
    v2f accA[8], accB[8], accC[8];   // (den,num0) (num1,num2) (num3,num4)
    #pragma unroll
    for (int i = 0; i < 8; i++) {
        accA[i] = (v2f){0.f, 0.f}; accB[i] = (v2f){0.f, 0.f}; accC[i] = (v2f){0.f, 0.f};
    }
    const float* Th = T + ((size_t)h * NT + c * 2048) * 8;
    const unsigned* mbase = pw + (l >> 5) * 64 + w * 8;   // + q*128 per step
    int lsh = l & 31;
    for (int q = 0; q < 32; q++) {
        const float* tp = Th + (size_t)(q * 64 + l) * 8;
        f32x4 t0 = *(const f32x4*)tp;
        f32x4 t1 = *(const f32x4*)(tp + 4);
        v2f ffp = {t0.x, t0.y};          // (F, Fp)
        v2f g01 = {t0.z, t0.w};          // (1, g0)
        v2f g12 = {t1.x, t1.y};          // (g1, g2)
        v2f g34 = {t1.z, t1.w};          // (g3, g4)
        uint4 ma = *(const uint4*)(mbase + q * 128);       // rows i=0..3
        uint4 mb = *(const uint4*)(mbase + q * 128 + 4);   // rows i=4..7
        unsigned wv[8] = {ma.x, ma.y, ma.z, ma.w, mb.x, mb.y, mb.z, mb.w};
        #pragma unroll
        for (int i = 0; i < 8; i++) {
            float bm = (float)((wv[i] >> lsh) & 1u);       // v_bfe + v_cvt
            v2f pab;
            asm("v_pk_mul_f32 %0, %1, %2" : "=v"(pab) : "v"(ffp), "s"(epk[i]));
            float pp = fmaxf(pab.x, pab.y) * bm;           // exp(leaky) * adj
            v2f ppv; ppv.x = pp; ppv.y = pp;
            asm("v_pk_fma_f32 %0, %1, %2, %0" : "+v"(accA[i]) : "v"(ppv), "v"(g01));
            asm("v_pk_fma_f32 %0, %1, %2, %0" : "+v"(accB[i]) : "v"(ppv), "v"(g12));
            asm("v_pk_fma_f32 %0, %1, %2, %0" : "+v"(accC[i]) : "v"(ppv), "v"(g34));
        }
    }
    // 3-step octet butterfly -> 8 partials per (row, value)
    #pragma unroll
    for (int i = 0; i < 8; i++) {
        float v[6];
        v[0] = accA[i].x; v[1] = accA[i].y;
        v[2] = accB[i].x; v[3] = accB[i].y;
        v[4] = accC[i].x; v[5] = accC[i].y;
        #pragma unroll
        for (int off = 1; off < 8; off <<= 1)
            #pragma unroll
            for (int k = 0; k < 6; k++) v[k] += __shfl_xor(v[k], off);
        if ((l & 7) == 0) {
            float* dst = part + ((((size_t)c * NW + n0 + i) * 8 + h) * 8 + (l >> 3)) * 8;
            #pragma unroll
            for (int k = 0; k < 6; k++) dst[k] = v[k];
        }
    }
}

// ---- combine chunks(2) x octet-partials(8) + heads -> hf[n][5] ----
__global__ __launch_bounds__(256) void k_gat2_comb(const float* __restrict__ part,
                                                   float* __restrict__ hf) {
    int idx = blockIdx.x * 256 + threadIdx.x;  // n*8 + h
    int n = idx >> 3, h = idx & 7;
    float den = 0, num[5] = {0,0,0,0,0};
    #pragma unroll
    for (int cc = 0; cc < 2; cc++) {
        #pragma unroll
        for (int s = 0; s < 8; s++) {
            const float* p = part + ((((size_t)cc * NW + n) * 8 + h) * 8 + s) * 8;
            float4 a = *(const float4*)p;
            float4 bq = *(const float4*)(p + 4);
            den += a.x;
            num[0] += a.y; num[1] += a.z; num[2] += a.w;
            num[3] += bq.x; num[4] += bq.y;
        }
    }
    float inv = 1.0f / (den * 8.0f);
    float v[5];
    #pragma unroll
    for (int j = 0; j < 5; j++) v[j] = num[j] * inv;
    #pragma unroll
    for (int off = 1; off < 8; off <<= 1)
        #pragma unroll
        for (int j = 0; j < 5; j++) v[j] += __shfl_xor(v[j], off);
    if (h == 0) {
        #pragma unroll
        for (int j = 0; j < 5; j++) hf[n * 5 + j] = v[j];
    }
}

// ---- out[b][j] = (input[b].hf[:,j]) / sum(input[b]) + c[j] + b_fc[j] ----
__global__ __launch_bounds__(256) void k_final(
    const float* __restrict__ input, const float* __restrict__ hf,
    const float* __restrict__ cvec, const float* __restrict__ b_fc,
    float* __restrict__ out)
{
    int b = blockIdx.x, t = threadIdx.x;
    const float4* row4 = (const float4*)(input + (size_t)b * NW);
    const float4* hf4 = (const float4*)hf;
    float s = 0.f, a[5] = {0.f, 0.f, 0.f, 0.f, 0.f};
    for (int idx = t; idx < NW / 4; idx += 256) {
        float4 x = row4[idx];
        float f[20];
        #pragma unroll
        for (int q = 0; q < 5; q++) *(float4*)(f + 4 * q) = hf4[idx * 5 + q];
        s += x.x + x.y + x.z + x.w;
        #pragma unroll
        for (int j = 0; j < 5; j++)
            a[j] += x.x * f[j] + x.y * f[5 + j] + x.z * f[10 + j] + x.w * f[15 + j];
    }
    #pragma unroll
    for (int off = 1; off < 64; off <<= 1) {
        s += __shfl_xor(s, off);
        #pragma unroll
        for (int j = 0; j < 5; j++) a[j] += __shfl_xor(a[j], off);
    }
    __shared__ float red[4][6];
    int w = t >> 6, l = t & 63;
    if (l == 0) { red[w][0] = s; for (int j = 0; j < 5; j++) red[w][j + 1] = a[j]; }
    __syncthreads();
    if (t < 5) {
        float st = red[0][0] + red[1][0] + red[2][0] + red[3][0];
        float aj = red[0][t + 1] + red[1][t + 1] + red[2][t + 1] + red[3][t + 1];
        out[b * 5 + t] = aj / st + cvec[t] + b_fc[t];
    }
}

extern "C" void kernel_launch(void* const* d_in, const int* in_sizes, int n_in,
                              void* d_out, int out_size, void* d_ws, size_t ws_size,
                              hipStream_t stream) {
    const float* input   = (const float*)d_in[0];
    const float* pf      = (const float*)d_in[1];
    const float* wf      = (const float*)d_in[2];
    const float* w1      = (const float*)d_in[3];
    const float* a_src1  = (const float*)d_in[4];
    const float* a_dst1  = (const float*)d_in[5];
    const float* b1      = (const float*)d_in[6];
    const float* w2      = (const float*)d_in[7];
    const float* a_src2  = (const float*)d_in[8];
    const float* a_dst2  = (const float*)d_in[9];
    const float* b2      = (const float*)d_in[10];
    const float* W_fc    = (const float*)d_in[11];
    const float* b_fc    = (const float*)d_in[12];
    const int* pern_adj  = (const int*)d_in[13];
    const int* wp_adj    = (const int*)d_in[14];
    float* out = (float*)d_out;

    char* ws = (char*)d_ws;
    unsigned short* abf    = (unsigned short*)(ws);            // 2 MB
    unsigned short* btbf   = (unsigned short*)(ws + 2097152);  // 1 MB
    float*          hp1    = (float*)(ws + 3145728);           // 512 KB
    float*          ss1    = (float*)(ws + 3670016);           // 16 KB
    float*          sd1    = (float*)(ws + 3686400);           // 16 KB
    float*          Etab   = (float*)(ws + 3833856);           // 128 KB
    float*          Eptab  = (float*)(ws + 3964928);           // 128 KB
    float*          T      = (float*)(ws + 4096000);           // 1 MB
    float*          hf     = (float*)(ws + 5144576);           // 70 KB
    float*          cvec   = (float*)(ws + 5216256);           // 64 B
    unsigned*       maskT  = (unsigned*)(ws + 5216512);        // 1.75 MB
    float*          gpart  = (float*)(ws + 7051520);           // 4 MB
    float*          part   = (float*)(ws + 11245824);          // 14.7 MB

    k_prep<<<2177, 256, 0, stream>>>(wf, pf, w1, a_src1, a_dst1, w2, b2, W_fc,
                                     wp_adj, abf, btbf, hp1, ss1, sd1, maskT, cvec);
    k_gat1_attn<<<256, 256, 0, stream>>>(pern_adj, hp1, ss1, sd1, b1, abf);
    k_gemm_hp2<<<512, 256, 0, stream>>>(abf, btbf, a_src2, a_dst2, W_fc, gpart);
    k_comb_hp2<<<128, 256, 0, stream>>>(gpart, Etab, Eptab, T);
    k_gat2_attn<<<896, 512, 0, stream>>>(maskT, Etab, Eptab, T, part);
    k_gat2_comb<<<112, 256, 0, stream>>>(part, hf);
    k_final<<<1024, 256, 0, stream>>>(input, hf, cvec, b_fc, out);
}

// Round 9
// 274.422 us; speedup vs baseline: 1.1442x; 1.0271x over previous
//
#include <hip/hip_runtime.h>
#include <hip/hip_bf16.h>
#include <math.h>

#define NP 512
#define NW 3584
#define NT 4096
#define FIN 256
#define H1 8
#define O1 32
#define H2 8
#define O2 256
#define NEG 0.2f

typedef __attribute__((ext_vector_type(8))) short bf16x8;
typedef __attribute__((ext_vector_type(4))) float f32x4;
typedef __attribute__((ext_vector_type(2))) float v2f;
typedef unsigned long long u64;

__device__ __forceinline__ unsigned short f2bf(float f) {
    unsigned u = __float_as_uint(f);
    unsigned r = (u + 0x7FFF + ((u >> 16) & 1)) >> 16;
    return (unsigned short)r;
}

__device__ __forceinline__ float fast_tanh(float x) {
    float ex = __expf(2.0f * x);
    return 1.0f - 2.0f / (ex + 1.0f);   // saturates to +-1
}

// ===== fused prep: conv_word | gat1_hp | conv_w2(transpose) | pack_adj(u64-T) | cvec
// grid = 896 + 256 + 128 + 896 + 1 = 2177 blocks of 256
__global__ __launch_bounds__(256) void k_prep(
    const float* __restrict__ wf, const float* __restrict__ pf,
    const float* __restrict__ w1, const float* __restrict__ a_src1,
    const float* __restrict__ a_dst1, const float* __restrict__ w2,
    const float* __restrict__ b2, const float* __restrict__ W_fc,
    const int* __restrict__ wp_adj,
    unsigned short* __restrict__ abf, unsigned short* __restrict__ btbf,
    float* __restrict__ hp1, float* __restrict__ ss1, float* __restrict__ sd1,
    u64* __restrict__ maskT64, float* __restrict__ cvec)
{
    __shared__ float tile[64][65];   // 16.6 KB (conv_w2 transpose)
    __shared__ float feat[2][FIN];
    __shared__ float red[4][5];
    int blk = blockIdx.x;
    int t = threadIdx.x;
    if (blk < 896) {
        // conv_word: float4 -> ushort4
        int idx4 = blk * 256 + t;
        float4 x = ((const float4*)wf)[idx4];
        ushort4 y;
        y.x = f2bf(x.x); y.y = f2bf(x.y); y.z = f2bf(x.z); y.w = f2bf(x.w);
        ((ushort4*)abf)[idx4] = y;
    } else if (blk < 1152) {
        // gat1_hp: 2 rows per block
        int n0 = (blk - 896) * 2;
        feat[0][t] = pf[n0 * FIN + t];
        feat[1][t] = pf[(n0 + 1) * FIN + t];
        __syncthreads();
        int h = t >> 5, o = t & 31;
        float acc0 = 0.f, acc1 = 0.f;
        const float* wcol = w1 + h * FIN * O1 + o;
        #pragma unroll 4
        for (int f = 0; f < FIN; f++) {
            float w = wcol[f * O1];
            acc0 += feat[0][f] * w;
            acc1 += feat[1][f] * w;
        }
        hp1[n0 * 256 + t] = acc0;
        hp1[(n0 + 1) * 256 + t] = acc1;
        float as = a_src1[h * O1 + o];
        float ad = a_dst1[h * O1 + o];
        float accs[2] = {acc0, acc1};
        #pragma unroll
        for (int i = 0; i < 2; i++) {
            float th = tanhf(accs[i]);
            float vs = th * as, vd = th * ad;
            #pragma unroll
            for (int off = 1; off < 32; off <<= 1) {
                vs += __shfl_xor(vs, off);
                vd += __shfl_xor(vd, off);
            }
            if (o == 0) { ss1[h * NP + n0 + i] = vs; sd1[h * NP + n0 + i] = vd; }
        }
    } else if (blk < 1280) {
        // conv_w2: LDS-tiled transpose [h][f][o] -> bf16 [h][o][f], coalesced both ways
        int blk2 = blk - 1152;
        int h = blk2 >> 4;
        int f0 = ((blk2 >> 2) & 3) * 64;
        int o0 = (blk2 & 3) * 64;
        #pragma unroll
        for (int rr = 0; rr < 16; rr++) {
            int f = rr * 4 + (t >> 6);
            int o = t & 63;
            tile[f][o] = w2[((size_t)(h * FIN + f0 + f)) * O2 + o0 + o];
        }
        __syncthreads();
        #pragma unroll
        for (int rr = 0; rr < 16; rr++) {
            int o = rr * 4 + (t >> 6);
            int f = t & 63;
            btbf[((size_t)(h * O2 + o0 + o)) * FIN + f0 + f] = f2bf(tile[f][o]);
        }
    } else if (blk < 2176) {
        // pack_adj -> u64 TRANSPOSED: maskT64[qw(64)][row(3584)]
        int w = t >> 6, l = t & 63;
        int r = (blk - 1280) * 4 + w;
        const int4* row = (const int4*)(wp_adj + (size_t)r * NT);
        for (int c4 = 0; c4 < 16; c4++) {
            int4 x = row[c4 * 64 + l];
            u64 nib = (u64)((x.x != 0 ? 1 : 0) | (x.y != 0 ? 2 : 0) |
                            (x.z != 0 ? 4 : 0) | (x.w != 0 ? 8 : 0));
            u64 v = nib << (4 * (l & 15));
            v |= __shfl_xor(v, 1);
            v |= __shfl_xor(v, 2);
            v |= __shfl_xor(v, 4);
            v |= __shfl_xor(v, 8);
            if ((l & 15) == 0) {
                int qw = c4 * 4 + (l >> 4);    // u64 column-qword index 0..63
                maskT64[(size_t)qw * NW + r] = v;
            }
        }
    } else {
        // cvec: c[j] = b2 . W_fc[:,j]
        float v[5];
        #pragma unroll
        for (int j = 0; j < 5; j++) v[j] = b2[t] * W_fc[t * 5 + j];
        #pragma unroll
        for (int off = 1; off < 64; off <<= 1)
            #pragma unroll
            for (int j = 0; j < 5; j++) v[j] += __shfl_xor(v[j], off);
        int w = t >> 6, l = t & 63;
        if (l == 0) { for (int j = 0; j < 5; j++) red[w][j] = v[j]; }
        __syncthreads();
        if (t == 0)
            for (int j = 0; j < 5; j++) cvec[j] = red[0][j] + red[1][j] + red[2][j] + red[3][j];
    }
}

// ---- GAT1 attention: 2 query rows per block (256 blocks) ----
__global__ __launch_bounds__(256) void k_gat1_attn(
    const int* __restrict__ adj, const float* __restrict__ hp1,
    const float* __restrict__ ss1, const float* __restrict__ sd1,
    const float* __restrict__ b1, unsigned short* __restrict__ abf)
{
    __shared__ float p[2][H1][NP];   // 32 KB
    __shared__ float den[2][H1];
    int t = threadIdx.x;
    int n0 = blockIdx.x * 2;
    for (int rr = 0; rr < 32; rr++) {
        int idx = rr * 256 + t;       // i(1) h(3) m(9)
        int i = idx >> 12, h = (idx >> 9) & 7, m = idx & 511;
        float a = adj[(n0 + i) * NP + m] > 0 ? 1.0f : 0.0f;
        float e = ss1[h * NP + n0 + i] + sd1[h * NP + m];
        e = fmaxf(e, NEG * e);
        p[i][h][m] = a * __expf(e);
    }
    __syncthreads();
    int w = t >> 6, l = t & 63;
    {
        int i = w & 1;
        #pragma unroll
        for (int hh = 0; hh < 4; hh++) {
            int h = (w >> 1) * 4 + hh;
            float s = 0;
            #pragma unroll
            for (int q = 0; q < 8; q++) s += p[i][h][l + 64 * q];
            #pragma unroll
            for (int off = 1; off < 64; off <<= 1) s += __shfl_xor(s, off);
            if (l == 0) den[i][h] = s;
        }
    }
    __syncthreads();
    int h = t >> 5, o = t & 31;
    float acc[2] = {0, 0};
    #pragma unroll 4
    for (int m = 0; m < NP; m++) {
        float v = hp1[m * 256 + t];
        acc[0] += p[0][h][m] * v;
        acc[1] += p[1][h][m] * v;
    }
    float bo = b1[o];
    #pragma unroll
    for (int i = 0; i < 2; i++) {
        float r = acc[i] / den[i][h] + bo;
        r = r > 0.f ? r : expm1f(r);   // elu
        abf[(NW + n0 + i) * FIN + t] = f2bf(r);
    }
}

// ---- hp2 GEMM with FUSED ss2/sd2/G reduction epilogue ----
__global__ __launch_bounds__(256) void k_gemm_hp2(
    const unsigned short* __restrict__ abf, const unsigned short* __restrict__ btbf,
    const float* __restrict__ a_src2, const float* __restrict__ a_dst2,
    const float* __restrict__ W_fc, float* __restrict__ gpart)
{
    int bid = blockIdx.x;
    int h = bid >> 6;
    int rem = bid & 63;
    int mt = rem >> 1, nt = rem & 1;
    int w = threadIdx.x >> 6, l = threadIdx.x & 63;
    int m0 = mt * 128 + (w >> 1) * 64;
    int n0 = nt * 128 + (w & 1) * 64;
    int lr = l & 15, lq = l >> 4;
    const unsigned short* bbase = btbf + h * O2 * FIN;
    f32x4 acc[4][4];
    #pragma unroll
    for (int i = 0; i < 4; i++)
        #pragma unroll
        for (int j = 0; j < 4; j++) acc[i][j] = (f32x4){0.f, 0.f, 0.f, 0.f};
    for (int k = 0; k < FIN; k += 32) {
        bf16x8 a[4], b[4];
        int kc = k + lq * 8;
        #pragma unroll
        for (int i = 0; i < 4; i++)
            a[i] = *(const bf16x8*)(abf + (m0 + i * 16 + lr) * FIN + kc);
        #pragma unroll
        for (int j = 0; j < 4; j++)
            b[j] = *(const bf16x8*)(bbase + (n0 + j * 16 + lr) * FIN + kc);
        #pragma unroll
        for (int i = 0; i < 4; i++)
            #pragma unroll
            for (int j = 0; j < 4; j++)
                acc[i][j] = __builtin_amdgcn_mfma_f32_16x16x32_bf16(a[i], b[j], acc[i][j], 0, 0, 0);
    }
    int slice = nt * 2 + (w & 1);
    float as[4], ad[4], wfc[4][5];
    #pragma unroll
    for (int j = 0; j < 4; j++) {
        int col = n0 + j * 16 + lr;
        as[j] = a_src2[h * O2 + col];
        ad[j] = a_dst2[h * O2 + col];
        #pragma unroll
        for (int jj = 0; jj < 5; jj++) wfc[j][jj] = W_fc[col * 5 + jj];
    }
    float* base = gpart + ((size_t)h * 4 + slice) * NT * 8;
    #pragma unroll
    for (int i = 0; i < 4; i++) {
        #pragma unroll
        for (int r = 0; r < 4; r++) {
            float s[7] = {0,0,0,0,0,0,0};
            #pragma unroll
            for (int j = 0; j < 4; j++) {
                float x = acc[i][j][r];
                float th = fast_tanh(x);
                s[0] += th * as[j];
                s[1] += th * ad[j];
                #pragma unroll
                for (int jj = 0; jj < 5; jj++) s[2 + jj] += x * wfc[j][jj];
            }
            #pragma unroll
            for (int off = 1; off < 16; off <<= 1)
                #pragma unroll
                for (int q = 0; q < 7; q++) s[q] += __shfl_xor(s[q], off);
            if (lr == 0) {
                int m = m0 + i * 16 + lq * 4 + r;
                float* dst = base + (size_t)m * 8;
                #pragma unroll
                for (int q = 0; q < 7; q++) dst[q] = s[q];
            }
        }
    }
}

// ---- combine slices -> Etab/Eptab (query side) + T={F,Fp,1,g0,g1,g2,g3,g4} (key side) ----
__global__ __launch_bounds__(256) void k_comb_hp2(
    const float* __restrict__ gpart,
    float* __restrict__ Etab, float* __restrict__ Eptab, float* __restrict__ T)
{
    int idx = blockIdx.x * 256 + threadIdx.x;   // h*NT + m
    float s[7] = {0,0,0,0,0,0,0};
    #pragma unroll
    for (int sl = 0; sl < 4; sl++) {
        const float* p = gpart + (((size_t)(idx >> 12) * 4 + sl) * NT + (idx & (NT - 1))) * 8;
        #pragma unroll
        for (int q = 0; q < 7; q++) s[q] += p[q];
    }
    Etab[idx]  = __expf(s[0]);
    Eptab[idx] = __expf(NEG * s[0]);
    float4 t0 = {__expf(s[1]), __expf(NEG * s[1]), 1.0f, s[2]};
    float4 t1 = {s[3], s[4], s[5], s[6]};
    *(float4*)(T + (size_t)idx * 8)     = t0;
    *(float4*)(T + (size_t)idx * 8 + 4) = t1;
}

// ---- GAT2 attention: scalar-load masks (s_load_dwordx16), plain-float accumulators ----
// grid: nb(112) x h(8) x c(2), 256 thr; wave owns 8 rows; lane owns m = c*2048+q*64+l
// part[(((c*NW+n)*8+h)*8+s)*8 + {den,num0..4,pad,pad}]
__global__ __launch_bounds__(256) void k_gat2_attn(
    const u64* __restrict__ maskT64, const float* __restrict__ Etab,
    const float* __restrict__ Eptab, const float* __restrict__ T,
    float* __restrict__ part)
{
    int t = threadIdx.x;
    int w = t >> 6, l = t & 63;
    int b = blockIdx.x;
    int nb = b % 112;
    int h  = (b / 112) & 7;
    int c  = b / 896;
    int n0 = __builtin_amdgcn_readfirstlane(nb * 32 + w * 8);  // scalar row base
    u64 epk[8];                          // (E, Ep) per row as sgpr pair
    #pragma unroll
    for (int i = 0; i < 8; i++) {
        int r = h * NT + n0 + i;
        unsigned e  = __builtin_amdgcn_readfirstlane(__float_as_uint(Etab[r]));
        unsigned ep = __builtin_amdgcn_readfirstlane(__float_as_uint(Eptab[r]));
        epk[i] = ((u64)ep << 32) | e;
    }
    float den[8] = {0,0,0,0,0,0,0,0};
    float num[8][5] = {{0}};
    const float* Th = T + ((size_t)h * NT + c * 2048) * 8;
    for (int q = 0; q < 32; q++) {
        const float* tp = Th + (size_t)(q * 64 + l) * 8;
        f32x4 t0 = *(const f32x4*)tp;    // {F, Fp, 1, g0}
        f32x4 t1 = *(const f32x4*)(tp + 4);  // {g1, g2, g3, g4}
        v2f ffp = {t0.x, t0.y};
        // scalar (wave-uniform) mask block: 8 consecutive u64 -> s_load_dwordx16
        size_t moff = (size_t)(c * 32 + q) * NW + n0;
        const u64* mq = maskT64 + moff;
        #pragma unroll
        for (int i = 0; i < 8; i++) {
            u64 wv = mq[i];
            unsigned wlo = __builtin_amdgcn_readfirstlane((unsigned)wv);
            unsigned whi = __builtin_amdgcn_readfirstlane((unsigned)(wv >> 32));
            u64 word = ((u64)whi << 32) | wlo;
            v2f pab;
            asm("v_pk_mul_f32 %0, %1, %2" : "=v"(pab) : "v"(ffp), "s"(epk[i]));
            float pp0 = fmaxf(pab.x, pab.y);              // exp(leaky(ss+sd))
            float pp;
            asm("v_cndmask_b32 %0, 0, %1, %2" : "=v"(pp) : "v"(pp0), "s"(word));
            den[i] += pp;
            num[i][0] = fmaf(pp, t0.w, num[i][0]);
            num[i][1] = fmaf(pp, t1.x, num[i][1]);
            num[i][2] = fmaf(pp, t1.y, num[i][2]);
            num[i][3] = fmaf(pp, t1.z, num[i][3]);
            num[i][4] = fmaf(pp, t1.w, num[i][4]);
        }
    }
    // 3-step octet butterfly -> 8 partials per (row, value)
    #pragma unroll
    for (int i = 0; i < 8; i++) {
        float v[6];
        v[0] = den[i];
        #pragma unroll
        for (int j = 0; j < 5; j++) v[1 + j] = num[i][j];
        #pragma unroll
        for (int off = 1; off < 8; off <<= 1)
            #pragma unroll
            for (int k = 0; k < 6; k++) v[k] += __shfl_xor(v[k], off);
        if ((l & 7) == 0) {
            float* dst = part + ((((size_t)c * NW + n0 + i) * 8 + h) * 8 + (l >> 3)) * 8;
            #pragma unroll
            for (int k = 0; k < 6; k++) dst[k] = v[k];
        }
    }
}

// ---- combine chunks(2) x octet-partials(8) + heads -> hf[n][5] ----
__global__ __launch_bounds__(256) void k_gat2_comb(const float* __restrict__ part,
                                                   float* __restrict__ hf) {
    int idx = blockIdx.x * 256 + threadIdx.x;  // n*8 + h
    int n = idx >> 3, h = idx & 7;
    float den = 0, num[5] = {0,0,0,0,0};
    #pragma unroll
    for (int cc = 0; cc < 2; cc++) {
        #pragma unroll
        for (int s = 0; s < 8; s++) {
            const float* p = part + ((((size_t)cc * NW + n) * 8 + h) * 8 + s) * 8;
            float4 a = *(const float4*)p;
            float4 bq = *(const float4*)(p + 4);
            den += a.x;
            num[0] += a.y; num[1] += a.z; num[2] += a.w;
            num[3] += bq.x; num[4] += bq.y;
        }
    }
    float inv = 1.0f / (den * 8.0f);
    float v[5];
    #pragma unroll
    for (int j = 0; j < 5; j++) v[j] = num[j] * inv;
    #pragma unroll
    for (int off = 1; off < 8; off <<= 1)
        #pragma unroll
        for (int j = 0; j < 5; j++) v[j] += __shfl_xor(v[j], off);
    if (h == 0) {
        #pragma unroll
        for (int j = 0; j < 5; j++) hf[n * 5 + j] = v[j];
    }
}

// ---- out[b][j] = (input[b].hf[:,j]) / sum(input[b]) + c[j] + b_fc[j] ----
__global__ __launch_bounds__(256) void k_final(
    const float* __restrict__ input, const float* __restrict__ hf,
    const float* __restrict__ cvec, const float* __restrict__ b_fc,
    float* __restrict__ out)
{
    int b = blockIdx.x, t = threadIdx.x;
    const float4* row4 = (const float4*)(input + (size_t)b * NW);
    const float4* hf4 = (const float4*)hf;
    float s = 0.f, a[5] = {0.f, 0.f, 0.f, 0.f, 0.f};
    for (int idx = t; idx < NW / 4; idx += 256) {
        float4 x = row4[idx];
        float f[20];
        #pragma unroll
        for (int q = 0; q < 5; q++) *(float4*)(f + 4 * q) = hf4[idx * 5 + q];
        s += x.x + x.y + x.z + x.w;
        #pragma unroll
        for (int j = 0; j < 5; j++)
            a[j] += x.x * f[j] + x.y * f[5 + j] + x.z * f[10 + j] + x.w * f[15 + j];
    }
    #pragma unroll
    for (int off = 1; off < 64; off <<= 1) {
        s += __shfl_xor(s, off);
        #pragma unroll
        for (int j = 0; j < 5; j++) a[j] += __shfl_xor(a[j], off);
    }
    __shared__ float red[4][6];
    int w = t >> 6, l = t & 63;
    if (l == 0) { red[w][0] = s; for (int j = 0; j < 5; j++) red[w][j + 1] = a[j]; }
    __syncthreads();
    if (t < 5) {
        float st = red[0][0] + red[1][0] + red[2][0] + red[3][0];
        float aj = red[0][t + 1] + red[1][t + 1] + red[2][t + 1] + red[3][t + 1];
        out[b * 5 + t] = aj / st + cvec[t] + b_fc[t];
    }
}

extern "C" void kernel_launch(void* const* d_in, const int* in_sizes, int n_in,
                              void* d_out, int out_size, void* d_ws, size_t ws_size,
                              hipStream_t stream) {
    const float* input   = (const float*)d_in[0];
    const float* pf      = (const float*)d_in[1];
    const float* wf      = (const float*)d_in[2];
    const float* w1      = (const float*)d_in[3];
    const float* a_src1  = (const float*)d_in[4];
    const float* a_dst1  = (const float*)d_in[5];
    const float* b1      = (const float*)d_in[6];
    const float* w2      = (const float*)d_in[7];
    const float* a_src2  = (const float*)d_in[8];
    const float* a_dst2  = (const float*)d_in[9];
    const float* b2      = (const float*)d_in[10];
    const float* W_fc    = (const float*)d_in[11];
    const float* b_fc    = (const float*)d_in[12];
    const int* pern_adj  = (const int*)d_in[13];
    const int* wp_adj    = (const int*)d_in[14];
    float* out = (float*)d_out;

    char* ws = (char*)d_ws;
    unsigned short* abf    = (unsigned short*)(ws);            // 2 MB
    unsigned short* btbf   = (unsigned short*)(ws + 2097152);  // 1 MB
    float*          hp1    = (float*)(ws + 3145728);           // 512 KB
    float*          ss1    = (float*)(ws + 3670016);           // 16 KB
    float*          sd1    = (float*)(ws + 3686400);           // 16 KB
    float*          Etab   = (float*)(ws + 3833856);           // 128 KB
    float*          Eptab  = (float*)(ws + 3964928);           // 128 KB
    float*          T      = (float*)(ws + 4096000);           // 1 MB
    float*          hf     = (float*)(ws + 5144576);           // 70 KB
    float*          cvec   = (float*)(ws + 5216256);           // 64 B
    u64*            maskT64= (u64*)(ws + 5216512);             // 1.75 MB
    float*          gpart  = (float*)(ws + 7051520);           // 4 MB
    float*          part   = (float*)(ws + 11245824);          // 14.7 MB

    k_prep<<<2177, 256, 0, stream>>>(wf, pf, w1, a_src1, a_dst1, w2, b2, W_fc,
                                     wp_adj, abf, btbf, hp1, ss1, sd1, maskT64, cvec);
    k_gat1_attn<<<256, 256, 0, stream>>>(pern_adj, hp1, ss1, sd1, b1, abf);
    k_gemm_hp2<<<512, 256, 0, stream>>>(abf, btbf, a_src2, a_dst2, W_fc, gpart);
    k_comb_hp2<<<128, 256, 0, stream>>>(gpart, Etab, Eptab, T);
    k_gat2_attn<<<1792, 256, 0, stream>>>(maskT64, Etab, Eptab, T, part);
    k_gat2_comb<<<112, 256, 0, stream>>>(part, hf);
    k_final<<<1024, 256, 0, stream>>>(input, hf, cvec, b_fc, out);
}

// Round 10
// 239.884 us; speedup vs baseline: 1.3090x; 1.1440x over previous
//
#include <hip/hip_runtime.h>
#include <hip/hip_bf16.h>
#include <math.h>

#define NP 512
#define NW 3584
#define NT 4096
#define FIN 256
#define H1 8
#define O1 32
#define H2 8
#define O2 256
#define NEG 0.2f

typedef __attribute__((ext_vector_type(8))) short bf16x8;
typedef __attribute__((ext_vector_type(4))) float f32x4;
typedef __attribute__((ext_vector_type(2))) float v2f;
typedef unsigned long long u64;

__device__ __forceinline__ unsigned short f2bf(float f) {
    unsigned u = __float_as_uint(f);
    unsigned r = (u + 0x7FFF + ((u >> 16) & 1)) >> 16;
    return (unsigned short)r;
}

__device__ __forceinline__ float fast_tanh(float x) {
    float ex = __expf(2.0f * x);
    return 1.0f - 2.0f / (ex + 1.0f);   // saturates to +-1
}

// ===== fused prep: conv_word | gat1_hp | conv_w2(transpose) | pack_adj(u64-T) | cvec
// grid = 896 + 256 + 128 + 896 + 1 = 2177 blocks of 256
__global__ __launch_bounds__(256) void k_prep(
    const float* __restrict__ wf, const float* __restrict__ pf,
    const float* __restrict__ w1, const float* __restrict__ a_src1,
    const float* __restrict__ a_dst1, const float* __restrict__ w2,
    const float* __restrict__ b2, const float* __restrict__ W_fc,
    const int* __restrict__ wp_adj,
    unsigned short* __restrict__ abf, unsigned short* __restrict__ btbf,
    float* __restrict__ hp1, float* __restrict__ ss1, float* __restrict__ sd1,
    u64* __restrict__ maskT64, float* __restrict__ cvec)
{
    __shared__ float tile[64][65];   // 16.6 KB (conv_w2 transpose)
    __shared__ float feat[2][FIN];
    __shared__ float red[4][5];
    int blk = blockIdx.x;
    int t = threadIdx.x;
    if (blk < 896) {
        // conv_word: float4 -> ushort4
        int idx4 = blk * 256 + t;
        float4 x = ((const float4*)wf)[idx4];
        ushort4 y;
        y.x = f2bf(x.x); y.y = f2bf(x.y); y.z = f2bf(x.z); y.w = f2bf(x.w);
        ((ushort4*)abf)[idx4] = y;
    } else if (blk < 1152) {
        // gat1_hp: 2 rows per block
        int n0 = (blk - 896) * 2;
        feat[0][t] = pf[n0 * FIN + t];
        feat[1][t] = pf[(n0 + 1) * FIN + t];
        __syncthreads();
        int h = t >> 5, o = t & 31;
        float acc0 = 0.f, acc1 = 0.f;
        const float* wcol = w1 + h * FIN * O1 + o;
        #pragma unroll 4
        for (int f = 0; f < FIN; f++) {
            float w = wcol[f * O1];
            acc0 += feat[0][f] * w;
            acc1 += feat[1][f] * w;
        }
        hp1[n0 * 256 + t] = acc0;
        hp1[(n0 + 1) * 256 + t] = acc1;
        float as = a_src1[h * O1 + o];
        float ad = a_dst1[h * O1 + o];
        float accs[2] = {acc0, acc1};
        #pragma unroll
        for (int i = 0; i < 2; i++) {
            float th = tanhf(accs[i]);
            float vs = th * as, vd = th * ad;
            #pragma unroll
            for (int off = 1; off < 32; off <<= 1) {
                vs += __shfl_xor(vs, off);
                vd += __shfl_xor(vd, off);
            }
            if (o == 0) { ss1[h * NP + n0 + i] = vs; sd1[h * NP + n0 + i] = vd; }
        }
    } else if (blk < 1280) {
        // conv_w2: LDS-tiled transpose [h][f][o] -> bf16 [h][o][f], coalesced both ways
        int blk2 = blk - 1152;
        int h = blk2 >> 4;
        int f0 = ((blk2 >> 2) & 3) * 64;
        int o0 = (blk2 & 3) * 64;
        #pragma unroll
        for (int rr = 0; rr < 16; rr++) {
            int f = rr * 4 + (t >> 6);
            int o = t & 63;
            tile[f][o] = w2[((size_t)(h * FIN + f0 + f)) * O2 + o0 + o];
        }
        __syncthreads();
        #pragma unroll
        for (int rr = 0; rr < 16; rr++) {
            int o = rr * 4 + (t >> 6);
            int f = t & 63;
            btbf[((size_t)(h * O2 + o0 + o)) * FIN + f0 + f] = f2bf(tile[f][o]);
        }
    } else if (blk < 2176) {
        // pack_adj -> u64 TRANSPOSED: maskT64[qw(64)][row(3584)]
        int w = t >> 6, l = t & 63;
        int r = (blk - 1280) * 4 + w;
        const int4* row = (const int4*)(wp_adj + (size_t)r * NT);
        for (int c4 = 0; c4 < 16; c4++) {
            int4 x = row[c4 * 64 + l];
            u64 nib = (u64)((x.x != 0 ? 1 : 0) | (x.y != 0 ? 2 : 0) |
                            (x.z != 0 ? 4 : 0) | (x.w != 0 ? 8 : 0));
            u64 v = nib << (4 * (l & 15));
            v |= __shfl_xor(v, 1);
            v |= __shfl_xor(v, 2);
            v |= __shfl_xor(v, 4);
            v |= __shfl_xor(v, 8);
            if ((l & 15) == 0) {
                int qw = c4 * 4 + (l >> 4);    // u64 column-qword index 0..63
                maskT64[(size_t)qw * NW + r] = v;
            }
        }
    } else {
        // cvec: c[j] = b2 . W_fc[:,j]
        float v[5];
        #pragma unroll
        for (int j = 0; j < 5; j++) v[j] = b2[t] * W_fc[t * 5 + j];
        #pragma unroll
        for (int off = 1; off < 64; off <<= 1)
            #pragma unroll
            for (int j = 0; j < 5; j++) v[j] += __shfl_xor(v[j], off);
        int w = t >> 6, l = t & 63;
        if (l == 0) { for (int j = 0; j < 5; j++) red[w][j] = v[j]; }
        __syncthreads();
        if (t == 0)
            for (int j = 0; j < 5; j++) cvec[j] = red[0][j] + red[1][j] + red[2][j] + red[3][j];
    }
}

// ---- GAT1 attention: 2 query rows per block (256 blocks), deep-unrolled hp1 loop ----
__global__ __launch_bounds__(256) void k_gat1_attn(
    const int* __restrict__ adj, const float* __restrict__ hp1,
    const float* __restrict__ ss1, const float* __restrict__ sd1,
    const float* __restrict__ b1, unsigned short* __restrict__ abf)
{
    __shared__ float p[2][H1][NP];   // 32 KB
    __shared__ float den[2][H1];
    int t = threadIdx.x;
    int n0 = blockIdx.x * 2;
    for (int rr = 0; rr < 32; rr++) {
        int idx = rr * 256 + t;       // i(1) h(3) m(9)
        int i = idx >> 12, h = (idx >> 9) & 7, m = idx & 511;
        float a = adj[(n0 + i) * NP + m] > 0 ? 1.0f : 0.0f;
        float e = ss1[h * NP + n0 + i] + sd1[h * NP + m];
        e = fmaxf(e, NEG * e);
        p[i][h][m] = a * __expf(e);
    }
    __syncthreads();
    int w = t >> 6, l = t & 63;
    {
        int i = w & 1;
        #pragma unroll
        for (int hh = 0; hh < 4; hh++) {
            int h = (w >> 1) * 4 + hh;
            float s = 0;
            #pragma unroll
            for (int q = 0; q < 8; q++) s += p[i][h][l + 64 * q];
            #pragma unroll
            for (int off = 1; off < 64; off <<= 1) s += __shfl_xor(s, off);
            if (l == 0) den[i][h] = s;
        }
    }
    __syncthreads();
    int h = t >> 5, o = t & 31;
    float a0a = 0.f, a0b = 0.f, a1a = 0.f, a1b = 0.f;
    #pragma unroll 8
    for (int m = 0; m < NP; m += 2) {
        float v0 = hp1[m * 256 + t];
        float v1 = hp1[(m + 1) * 256 + t];
        a0a += p[0][h][m] * v0;
        a1a += p[1][h][m] * v0;
        a0b += p[0][h][m + 1] * v1;
        a1b += p[1][h][m + 1] * v1;
    }
    float acc[2] = {a0a + a0b, a1a + a1b};
    float bo = b1[o];
    #pragma unroll
    for (int i = 0; i < 2; i++) {
        float r = acc[i] / den[i][h] + bo;
        r = r > 0.f ? r : expm1f(r);   // elu
        abf[(NW + n0 + i) * FIN + t] = f2bf(r);
    }
}

// ---- hp2 GEMM: A-tile (128 x full-K) staged in LDS once; B streamed from L2 ----
// grid: b = mt(32)<<4 | h(8)<<1 | nt(2); block 256 thr, wave computes 64x64
__global__ __launch_bounds__(256) void k_gemm_hp2(
    const unsigned short* __restrict__ abf, const unsigned short* __restrict__ btbf,
    const float* __restrict__ a_src2, const float* __restrict__ a_dst2,
    const float* __restrict__ W_fc, float* __restrict__ gpart)
{
    __shared__ unsigned short As[128][264];   // 67.6 KB, +8-short pad (bank-safe)
    int b = blockIdx.x;
    int nt = b & 1, h = (b >> 1) & 7, mt = b >> 4;
    int t = threadIdx.x;
    int w = t >> 6, l = t & 63;
    int m0 = mt * 128;
    // stage A-tile: 16 rounds x 256 thr x 16B, coalesced
    {
        int row = t >> 5;            // 0..7 per round (+8 per round)
        int col8 = (t & 31) * 8;     // shorts
        #pragma unroll
        for (int u = 0; u < 16; u++)
            *(bf16x8*)(&As[u * 8 + row][col8]) =
                *(const bf16x8*)(abf + (size_t)(m0 + u * 8 + row) * FIN + col8);
    }
    __syncthreads();
    int am0 = (w >> 1) * 64;
    int n0 = nt * 128 + (w & 1) * 64;
    int lr = l & 15, lq = l >> 4;
    const unsigned short* bbase = btbf + h * O2 * FIN;
    f32x4 acc[4][4];
    #pragma unroll
    for (int i = 0; i < 4; i++)
        #pragma unroll
        for (int j = 0; j < 4; j++) acc[i][j] = (f32x4){0.f, 0.f, 0.f, 0.f};
    #pragma unroll
    for (int k = 0; k < FIN; k += 32) {
        bf16x8 a[4], bf[4];
        int kc = k + lq * 8;
        #pragma unroll
        for (int j = 0; j < 4; j++)
            bf[j] = *(const bf16x8*)(bbase + (size_t)(n0 + j * 16 + lr) * FIN + kc);
        #pragma unroll
        for (int i = 0; i < 4; i++)
            a[i] = *(const bf16x8*)(&As[am0 + i * 16 + lr][kc]);
        #pragma unroll
        for (int i = 0; i < 4; i++)
            #pragma unroll
            for (int j = 0; j < 4; j++)
                acc[i][j] = __builtin_amdgcn_mfma_f32_16x16x32_bf16(a[i], bf[j], acc[i][j], 0, 0, 0);
    }
    int slice = nt * 2 + (w & 1);
    float as[4], ad[4], wfc[4][5];
    #pragma unroll
    for (int j = 0; j < 4; j++) {
        int col = n0 + j * 16 + lr;
        as[j] = a_src2[h * O2 + col];
        ad[j] = a_dst2[h * O2 + col];
        #pragma unroll
        for (int jj = 0; jj < 5; jj++) wfc[j][jj] = W_fc[col * 5 + jj];
    }
    float* base = gpart + ((size_t)h * 4 + slice) * NT * 8;
    #pragma unroll
    for (int i = 0; i < 4; i++) {
        #pragma unroll
        for (int r = 0; r < 4; r++) {
            float s[7] = {0,0,0,0,0,0,0};
            #pragma unroll
            for (int j = 0; j < 4; j++) {
                float x = acc[i][j][r];
                float th = fast_tanh(x);
                s[0] += th * as[j];
                s[1] += th * ad[j];
                #pragma unroll
                for (int jj = 0; jj < 5; jj++) s[2 + jj] += x * wfc[j][jj];
            }
            #pragma unroll
            for (int off = 1; off < 16; off <<= 1)
                #pragma unroll
                for (int q = 0; q < 7; q++) s[q] += __shfl_xor(s[q], off);
            if (lr == 0) {
                int m = m0 + am0 + i * 16 + lq * 4 + r;
                float* dst = base + (size_t)m * 8;
                #pragma unroll
                for (int q = 0; q < 7; q++) dst[q] = s[q];
            }
        }
    }
}

// ---- combine slices -> Etab/Eptab (query side) + T={F,Fp,1,g0,g1,g2,g3,g4} (key side) ----
__global__ __launch_bounds__(256) void k_comb_hp2(
    const float* __restrict__ gpart,
    float* __restrict__ Etab, float* __restrict__ Eptab, float* __restrict__ T)
{
    int idx = blockIdx.x * 256 + threadIdx.x;   // h*NT + m
    float s[7] = {0,0,0,0,0,0,0};
    #pragma unroll
    for (int sl = 0; sl < 4; sl++) {
        const float* p = gpart + (((size_t)(idx >> 12) * 4 + sl) * NT + (idx & (NT - 1))) * 8;
        #pragma unroll
        for (int q = 0; q < 7; q++) s[q] += p[q];
    }
    Etab[idx]  = __expf(s[0]);
    Eptab[idx] = __expf(NEG * s[0]);
    float4 t0 = {__expf(s[1]), __expf(NEG * s[1]), 1.0f, s[2]};
    float4 t1 = {s[3], s[4], s[5], s[6]};
    *(float4*)(T + (size_t)idx * 8)     = t0;
    *(float4*)(T + (size_t)idx * 8 + 4) = t1;
}

// ---- GAT2 attention: scalar-load masks, plain-float accumulators ----
// grid: nb(112) x h(8) x c(2), 256 thr; wave owns 8 rows; lane owns m = c*2048+q*64+l
__global__ __launch_bounds__(256) void k_gat2_attn(
    const u64* __restrict__ maskT64, const float* __restrict__ Etab,
    const float* __restrict__ Eptab, const float* __restrict__ T,
    float* __restrict__ part)
{
    int t = threadIdx.x;
    int w = t >> 6, l = t & 63;
    int b = blockIdx.x;
    int nb = b % 112;
    int h  = (b / 112) & 7;
    int c  = b / 896;
    int n0 = __builtin_amdgcn_readfirstlane(nb * 32 + w * 8);  // scalar row base
    u64 epk[8];                          // (E, Ep) per row as sgpr pair
    #pragma unroll
    for (int i = 0; i < 8; i++) {
        int r = h * NT + n0 + i;
        unsigned e  = __builtin_amdgcn_readfirstlane(__float_as_uint(Etab[r]));
        unsigned ep = __builtin_amdgcn_readfirstlane(__float_as_uint(Eptab[r]));
        epk[i] = ((u64)ep << 32) | e;
    }
    float den[8] = {0,0,0,0,0,0,0,0};
    float num[8][5] = {{0}};
    const float* Th = T + ((size_t)h * NT + c * 2048) * 8;
    for (int q = 0; q < 32; q++) {
        const float* tp = Th + (size_t)(q * 64 + l) * 8;
        f32x4 t0 = *(const f32x4*)tp;    // {F, Fp, 1, g0}
        f32x4 t1 = *(const f32x4*)(tp + 4);  // {g1, g2, g3, g4}
        v2f ffp = {t0.x, t0.y};
        size_t moff = (size_t)(c * 32 + q) * NW + n0;
        const u64* mq = maskT64 + moff;
        #pragma unroll
        for (int i = 0; i < 8; i++) {
            u64 wv = mq[i];
            unsigned wlo = __builtin_amdgcn_readfirstlane((unsigned)wv);
            unsigned whi = __builtin_amdgcn_readfirstlane((unsigned)(wv >> 32));
            u64 word = ((u64)whi << 32) | wlo;
            v2f pab;
            asm("v_pk_mul_f32 %0, %1, %2" : "=v"(pab) : "v"(ffp), "s"(epk[i]));
            float pp0 = fmaxf(pab.x, pab.y);              // exp(leaky(ss+sd))
            float pp;
            asm("v_cndmask_b32 %0, 0, %1, %2" : "=v"(pp) : "v"(pp0), "s"(word));
            den[i] += pp;
            num[i][0] = fmaf(pp, t0.w, num[i][0]);
            num[i][1] = fmaf(pp, t1.x, num[i][1]);
            num[i][2] = fmaf(pp, t1.y, num[i][2]);
            num[i][3] = fmaf(pp, t1.z, num[i][3]);
            num[i][4] = fmaf(pp, t1.w, num[i][4]);
        }
    }
    #pragma unroll
    for (int i = 0; i < 8; i++) {
        float v[6];
        v[0] = den[i];
        #pragma unroll
        for (int j = 0; j < 5; j++) v[1 + j] = num[i][j];
        #pragma unroll
        for (int off = 1; off < 8; off <<= 1)
            #pragma unroll
            for (int k = 0; k < 6; k++) v[k] += __shfl_xor(v[k], off);
        if ((l & 7) == 0) {
            float* dst = part + ((((size_t)c * NW + n0 + i) * 8 + h) * 8 + (l >> 3)) * 8;
            #pragma unroll
            for (int k = 0; k < 6; k++) dst[k] = v[k];
        }
    }
}

// ---- combine chunks(2) x octet-partials(8) + heads -> hf[n][5] ----
__global__ __launch_bounds__(256) void k_gat2_comb(const float* __restrict__ part,
                                                   float* __restrict__ hf) {
    int idx = blockIdx.x * 256 + threadIdx.x;  // n*8 + h
    int n = idx >> 3, h = idx & 7;
    float den = 0, num[5] = {0,0,0,0,0};
    #pragma unroll
    for (int cc = 0; cc < 2; cc++) {
        #pragma unroll
        for (int s = 0; s < 8; s++) {
            const float* p = part + ((((size_t)cc * NW + n) * 8 + h) * 8 + s) * 8;
            float4 a = *(const float4*)p;
            float4 bq = *(const float4*)(p + 4);
            den += a.x;
            num[0] += a.y; num[1] += a.z; num[2] += a.w;
            num[3] += bq.x; num[4] += bq.y;
        }
    }
    float inv = 1.0f / (den * 8.0f);
    float v[5];
    #pragma unroll
    for (int j = 0; j < 5; j++) v[j] = num[j] * inv;
    #pragma unroll
    for (int off = 1; off < 8; off <<= 1)
        #pragma unroll
        for (int j = 0; j < 5; j++) v[j] += __shfl_xor(v[j], off);
    if (h == 0) {
        #pragma unroll
        for (int j = 0; j < 5; j++) hf[n * 5 + j] = v[j];
    }
}

// ---- out[b][j] = (input[b].hf[:,j]) / sum(input[b]) + c[j] + b_fc[j] ----
__global__ __launch_bounds__(256) void k_final(
    const float* __restrict__ input, const float* __restrict__ hf,
    const float* __restrict__ cvec, const float* __restrict__ b_fc,
    float* __restrict__ out)
{
    int b = blockIdx.x, t = threadIdx.x;
    const float4* row4 = (const float4*)(input + (size_t)b * NW);
    const float4* hf4 = (const float4*)hf;
    float s = 0.f, a[5] = {0.f, 0.f, 0.f, 0.f, 0.f};
    for (int idx = t; idx < NW / 4; idx += 256) {
        float4 x = row4[idx];
        float f[20];
        #pragma unroll
        for (int q = 0; q < 5; q++) *(float4*)(f + 4 * q) = hf4[idx * 5 + q];
        s += x.x + x.y + x.z + x.w;
        #pragma unroll
        for (int j = 0; j < 5; j++)
            a[j] += x.x * f[j] + x.y * f[5 + j] + x.z * f[10 + j] + x.w * f[15 + j];
    }
    #pragma unroll
    for (int off = 1; off < 64; off <<= 1) {
        s += __shfl_xor(s, off);
        #pragma unroll
        for (int j = 0; j < 5; j++) a[j] += __shfl_xor(a[j], off);
    }
    __shared__ float red[4][6];
    int w = t >> 6, l = t & 63;
    if (l == 0) { red[w][0] = s; for (int j = 0; j < 5; j++) red[w][j + 1] = a[j]; }
    __syncthreads();
    if (t < 5) {
        float st = red[0][0] + red[1][0] + red[2][0] + red[3][0];
        float aj = red[0][t + 1] + red[1][t + 1] + red[2][t + 1] + red[3][t + 1];
        out[b * 5 + t] = aj / st + cvec[t] + b_fc[t];
    }
}

extern "C" void kernel_launch(void* const* d_in, const int* in_sizes, int n_in,
                              void* d_out, int out_size, void* d_ws, size_t ws_size,
                              hipStream_t stream) {
    const float* input   = (const float*)d_in[0];
    const float* pf      = (const float*)d_in[1];
    const float* wf      = (const float*)d_in[2];
    const float* w1      = (const float*)d_in[3];
    const float* a_src1  = (const float*)d_in[4];
    const float* a_dst1  = (const float*)d_in[5];
    const float* b1      = (const float*)d_in[6];
    const float* w2      = (const float*)d_in[7];
    const float* a_src2  = (const float*)d_in[8];
    const float* a_dst2  = (const float*)d_in[9];
    const float* b2      = (const float*)d_in[10];
    const float* W_fc    = (const float*)d_in[11];
    const float* b_fc    = (const float*)d_in[12];
    const int* pern_adj  = (const int*)d_in[13];
    const int* wp_adj    = (const int*)d_in[14];
    float* out = (float*)d_out;

    char* ws = (char*)d_ws;
    unsigned short* abf    = (unsigned short*)(ws);            // 2 MB
    unsigned short* btbf   = (unsigned short*)(ws + 2097152);  // 1 MB
    float*          hp1    = (float*)(ws + 3145728);           // 512 KB
    float*          ss1    = (float*)(ws + 3670016);           // 16 KB
    float*          sd1    = (float*)(ws + 3686400);           // 16 KB
    float*          Etab   = (float*)(ws + 3833856);           // 128 KB
    float*          Eptab  = (float*)(ws + 3964928);           // 128 KB
    float*          T      = (float*)(ws + 4096000);           // 1 MB
    float*          hf     = (float*)(ws + 5144576);           // 70 KB
    float*          cvec   = (float*)(ws + 5216256);           // 64 B
    u64*            maskT64= (u64*)(ws + 5216512);             // 1.75 MB
    float*          gpart  = (float*)(ws + 7051520);           // 4 MB
    float*          part   = (float*)(ws + 11245824);          // 14.7 MB

    k_prep<<<2177, 256, 0, stream>>>(wf, pf, w1, a_src1, a_dst1, w2, b2, W_fc,
                                     wp_adj, abf, btbf, hp1, ss1, sd1, maskT64, cvec);
    k_gat1_attn<<<256, 256, 0, stream>>>(pern_adj, hp1, ss1, sd1, b1, abf);
    k_gemm_hp2<<<512, 256, 0, stream>>>(abf, btbf, a_src2, a_dst2, W_fc, gpart);
    k_comb_hp2<<<128, 256, 0, stream>>>(gpart, Etab, Eptab, T);
    k_gat2_attn<<<1792, 256, 0, stream>>>(maskT64, Etab, Eptab, T, part);
    k_gat2_comb<<<112, 256, 0, stream>>>(part, hf);
    k_final<<<1024, 256, 0, stream>>>(input, hf, cvec, b_fc, out);
}